// Round 9
// baseline (478.077 us; speedup 1.0000x reference)
//
#include <hip/hip_runtime.h>
#include <cmath>

#define F_IN 500
#define HD 64
#define NL 8
#define NRANK 3
#define NOUT 40
#define NGRP 300   // 297 real (m,l0) groups of 8 + 3 zero pads -> K = 2400
#define NCHUNK 75  // 2400 / 32

typedef __attribute__((ext_vector_type(8))) short short8v;
typedef __attribute__((ext_vector_type(4))) float float4v;

__device__ __forceinline__ float bf2f(ushort u) {
  union { unsigned int i; float f; } v;
  v.i = ((unsigned int)u) << 16;
  return v.f;
}
__device__ __forceinline__ float bflo(unsigned int u) {
  union { unsigned int i; float f; } v;
  v.i = u << 16;
  return v.f;
}
__device__ __forceinline__ float bfhi(unsigned int u) {
  union { unsigned int i; float f; } v;
  v.i = u & 0xffff0000u;
  return v.f;
}
__device__ __forceinline__ ushort f2bf(float f) {
  union { float f; unsigned int i; } v;
  v.f = f;
  unsigned int b = v.i;
  return (ushort)((b + 0x7FFFu + ((b >> 16) & 1u)) >> 16);
}

// ---------------- zero init (counts, bias bufs, Bfrag, padded colw) ----------------
__global__ __launch_bounds__(256) void k_zero(int* counts, float* linbuf, float* cbuf,
                                              ushort4* bfrag4, int2* colw, int epad, int N) {
  int i = blockIdx.x * 256 + threadIdx.x;
  if (i < N) counts[i] = 0;
  if (i < NOUT * HD) linbuf[i] = 0.f;
  if (i < NOUT) cbuf[i] = 0.f;
  if (i < NCHUNK * 3 * 64 * 2) bfrag4[i] = make_ushort4(0, 0, 0, 0);
  for (int j = i; j < epad; j += gridDim.x * 256) colw[j] = make_int2(0, 0);
}

__global__ __launch_bounds__(256) void k_count(const int* __restrict__ row, int* counts, int E) {
  int e = blockIdx.x * 256 + threadIdx.x;
  if (e < E) atomicAdd(&counts[row[e]], 1);
}

// ---------------- parallel scan over degrees PADDED to 16 (3 kernels) ----------------
__global__ __launch_bounds__(1024) void k_scan1(const int* __restrict__ counts, int* __restrict__ rowptr,
                                                int* __restrict__ bsum, int N) {
  __shared__ int sh[1024];
  int t = threadIdx.x, i = blockIdx.x * 1024 + t;
  int c = (i < N) ? ((counts[i] + 15) & ~15) : 0;
  sh[t] = c;
  __syncthreads();
  for (int d = 1; d < 1024; d <<= 1) {
    int v = (t >= d) ? sh[t - d] : 0;
    __syncthreads();
    sh[t] += v;
    __syncthreads();
  }
  if (i < N) rowptr[i] = sh[t] - c;  // block-local exclusive
  if (t == 1023) bsum[blockIdx.x] = sh[1023];
}

__global__ __launch_bounds__(64) void k_scan2(const int* __restrict__ bsum, int* __restrict__ boff, int G) {
  int t = threadIdx.x;
  int base = 0;
  for (int s = 0; s < G; s += 64) {
    int i = s + t;
    int v = (i < G) ? bsum[i] : 0;
    int orig = v;
    for (int d = 1; d < 64; d <<= 1) {
      int u = __shfl_up(v, d, 64);
      if (t >= d) v += u;
    }
    if (i < G) boff[i] = base + v - orig;
    base += __shfl(v, 63, 64);
  }
}

__global__ __launch_bounds__(1024) void k_scan3(int* __restrict__ rowptr, int* __restrict__ cursor,
                                                const int* __restrict__ boff,
                                                const int* __restrict__ counts, int N) {
  int i = blockIdx.x * 1024 + threadIdx.x;
  if (i < N) {
    int v = rowptr[i] + boff[blockIdx.x];
    rowptr[i] = v;
    cursor[i] = v;
    if (i == N - 1) rowptr[N] = v + ((counts[i] + 15) & ~15);
  }
}

__global__ __launch_bounds__(256) void k_fill(const int* __restrict__ row, const int* __restrict__ col,
                                              const float* __restrict__ w, int* cursor,
                                              int2* __restrict__ colw, int E) {
  int e = blockIdx.x * 256 + threadIdx.x;
  if (e < E) {
    int r = row[e];
    int p = atomicAdd(&cursor[r], 1);
    colw[p] = make_int2(col[e] * HD, __float_as_int(w[e]));  // pre-scaled element offset
  }
}

// ---------------- W_in -> bf16 [64 cols][512 k], zero-padded ----------------
__global__ __launch_bounds__(256) void k_wcvt(const float* __restrict__ W, ushort* __restrict__ Wbf) {
  int i = blockIdx.x * 256 + threadIdx.x;
  if (i >= 64 * 512) return;
  int d = i >> 9, k = i & 511;
  Wbf[i] = (k < F_IN) ? f2bf(W[(size_t)k * HD + d]) : (ushort)0;
}

// ---------------- input GEMM via MFMA, depth-5 register prefetch, 1 wave/block ----------------
__global__ __launch_bounds__(64) void k_gemm_in(const float* __restrict__ x,
                                                const ushort* __restrict__ Wbf,
                                                const float* __restrict__ b,
                                                ushort* __restrict__ h0bf, int N) {
  int lane = threadIdx.x;
  int c15 = lane & 15, g4 = lane >> 4;
  int rowA = blockIdx.x * 16 + c15;
  if (rowA >= N) rowA = N - 1;  // clamp; results discarded at store
  const float* xr = x + (size_t)rowA * F_IN;
  int koff = g4 * 8;
  float4v acc[4];
#pragma unroll
  for (int ct = 0; ct < 4; ++ct) acc[ct] = (float4v){0.f, 0.f, 0.f, 0.f};

  // depth-5 prefetch ring: 10 float4 loads (160 B/lane) outstanding
  float4 pf[5][2];
#pragma unroll
  for (int i = 0; i < 5; ++i) {
    const float* p = xr + i * 32 + koff;
    pf[i][0] = *(const float4*)p;
    pf[i][1] = *(const float4*)(p + 4);
  }
#pragma unroll
  for (int kc = 0; kc < 15; ++kc) {
    float4 c0 = pf[kc % 5][0], c1 = pf[kc % 5][1];
    if (kc + 5 < 15) {
      const float* p = xr + (kc + 5) * 32 + koff;
      pf[kc % 5][0] = *(const float4*)p;
      pf[kc % 5][1] = *(const float4*)(p + 4);
    }
    short8v a;
    a[0] = (short)f2bf(c0.x); a[1] = (short)f2bf(c0.y);
    a[2] = (short)f2bf(c0.z); a[3] = (short)f2bf(c0.w);
    a[4] = (short)f2bf(c1.x); a[5] = (short)f2bf(c1.y);
    a[6] = (short)f2bf(c1.z); a[7] = (short)f2bf(c1.w);
    int kbase = kc * 32 + koff;
#pragma unroll
    for (int ct = 0; ct < 4; ++ct) {
      const short8v bb = *(const short8v*)&Wbf[((ct * 16 + c15) << 9) + kbase];
      acc[ct] = __builtin_amdgcn_mfma_f32_16x16x32_bf16(a, bb, acc[ct], 0, 0, 0);
    }
  }
  {  // chunk 15: floats 480..499 valid
    int kbase = 480 + koff;
    short8v a;
#pragma unroll
    for (int e = 0; e < 8; ++e) {
      int k = kbase + e;
      a[e] = (short)(k < F_IN ? f2bf(xr[k]) : (ushort)0);
    }
#pragma unroll
    for (int ct = 0; ct < 4; ++ct) {
      const short8v bb = *(const short8v*)&Wbf[((ct * 16 + c15) << 9) + kbase];
      acc[ct] = __builtin_amdgcn_mfma_f32_16x16x32_bf16(a, bb, acc[ct], 0, 0, 0);
    }
  }
  int mbase = blockIdx.x * 16 + g4 * 4;
#pragma unroll
  for (int ct = 0; ct < 4; ++ct) {
    int d = ct * 16 + c15;
    float bias = b[d];
#pragma unroll
    for (int r = 0; r < 4; ++r) {
      int m = mbase + r;
      if (m < N) {
        float v = acc[ct][r] + bias;
        h0bf[(size_t)m * HD + d] = f2bf(fmaxf(v, 0.f));
      }
    }
  }
}

// ---------------- per-layer matvec matrix in MFMA B-frag layout (once per layer) ----------------
__global__ __launch_bounds__(256) void k_mpack(const float* __restrict__ conv_W, ushort* __restrict__ Mfrag) {
  int l = blockIdx.x;
  const float* convW = conv_W + (size_t)l * HD * HD;
  ushort* out = Mfrag + (size_t)l * 512 * 8;
  float beta = logf(0.5f / (float)(l + 1) + 1.0f);
  int tid = threadIdx.x;
  for (int f = tid; f < 512; f += 256) {
    int kc = f >> 8, ct = (f >> 6) & 3, ln = f & 63;
    int kb = kc * 32 + ((ln >> 4) << 3);
    int col = (ct << 4) + (ln & 15);
    short8v vals;
#pragma unroll
    for (int e = 0; e < 8; ++e) {
      int k = kb + e;
      float v = beta * convW[(k << 6) + col] + ((k == col) ? (1.f - beta) : 0.f);
      vals[e] = (short)f2bf(v);
    }
    *(short8v*)&out[(size_t)f * 8] = vals;
  }
}

// ---------------- GCN2 layer: 2-row interleaved pair-gathers (16 in flight) + MFMA matvec ----------------
__global__ __launch_bounds__(256) void k_layer(const ushort* __restrict__ hin,
                                               const ushort* __restrict__ h0bf,
                                               const int* __restrict__ rowptrP, const int2* __restrict__ colw,
                                               const ushort* __restrict__ MfragL,
                                               ushort* __restrict__ hout, int N) {
  __shared__ ushort mfrag[512][8];
  __shared__ ushort sup[32][72];
  __shared__ ushort outt[32][72];
  int tid = threadIdx.x, wv = tid >> 6, t = tid & 63;
  int half = t >> 5, l31 = t & 31;
  {  // coalesced mfrag load (8 KB)
    const short8v* src = (const short8v*)MfragL;
    short8v* dst = (short8v*)&mfrag[0][0];
    dst[tid] = src[tid];
    dst[tid + 256] = src[tid + 256];
  }
  int n0 = blockIdx.x * 32;
  int base_row = n0 + wv * 8;
  int re = 0;
  if (t < 9) {
    int nn = base_row + t;
    if (nn <= N) re = rowptrP[nn];
  }
  const int4* cw4 = (const int4*)colw;
  for (int pr = 0; pr < 4; ++pr) {
    int rwA = wv * 8 + pr * 2, rwB = rwA + 1;
    int nA = n0 + rwA, nB = n0 + rwB;
    float aloA = 0.f, ahiA = 0.f, aloB = 0.f, ahiB = 0.f;
    if (nA < N) {
      int jA = __shfl(re, pr * 2, 64);
      int jeA = __shfl(re, pr * 2 + 1, 64);
      int jB = jeA;
      int jeB = (nB < N) ? __shfl(re, pr * 2 + 2, 64) : jeA;
      bool mA = jA < jeA, mB = jB < jeB;
      int4 qa0, qa1, qa2, qa3, qb0, qb1, qb2, qb3;
      if (mA) {
        int bi = (jA >> 1) + half;
        qa0 = cw4[bi]; qa1 = cw4[bi + 2]; qa2 = cw4[bi + 4]; qa3 = cw4[bi + 6];
        jA += 16;
      }
      if (mB) {
        int bi = (jB >> 1) + half;
        qb0 = cw4[bi]; qb1 = cw4[bi + 2]; qb2 = cw4[bi + 4]; qb3 = cw4[bi + 6];
        jB += 16;
      }
      while (mA || mB) {
        unsigned gA0, gA1, gA2, gA3, gA4, gA5, gA6, gA7;
        unsigned gB0, gB1, gB2, gB3, gB4, gB5, gB6, gB7;
        if (mA) {  // 8 pair-gathers for rows-pair A, back-to-back
          gA0 = *(const unsigned*)(hin + (unsigned)qa0.x + 2 * l31);
          gA1 = *(const unsigned*)(hin + (unsigned)qa0.z + 2 * l31);
          gA2 = *(const unsigned*)(hin + (unsigned)qa1.x + 2 * l31);
          gA3 = *(const unsigned*)(hin + (unsigned)qa1.z + 2 * l31);
          gA4 = *(const unsigned*)(hin + (unsigned)qa2.x + 2 * l31);
          gA5 = *(const unsigned*)(hin + (unsigned)qa2.z + 2 * l31);
          gA6 = *(const unsigned*)(hin + (unsigned)qa3.x + 2 * l31);
          gA7 = *(const unsigned*)(hin + (unsigned)qa3.z + 2 * l31);
        }
        if (mB) {  // 8 more for row B -> 16 outstanding
          gB0 = *(const unsigned*)(hin + (unsigned)qb0.x + 2 * l31);
          gB1 = *(const unsigned*)(hin + (unsigned)qb0.z + 2 * l31);
          gB2 = *(const unsigned*)(hin + (unsigned)qb1.x + 2 * l31);
          gB3 = *(const unsigned*)(hin + (unsigned)qb1.z + 2 * l31);
          gB4 = *(const unsigned*)(hin + (unsigned)qb2.x + 2 * l31);
          gB5 = *(const unsigned*)(hin + (unsigned)qb2.z + 2 * l31);
          gB6 = *(const unsigned*)(hin + (unsigned)qb3.x + 2 * l31);
          gB7 = *(const unsigned*)(hin + (unsigned)qb3.z + 2 * l31);
        }
        bool nmA = jA < jeA, nmB = jB < jeB;
        int4 pa0, pa1, pa2, pa3, pb0, pb1, pb2, pb3;
        if (nmA) {
          int bi = (jA >> 1) + half;
          pa0 = cw4[bi]; pa1 = cw4[bi + 2]; pa2 = cw4[bi + 4]; pa3 = cw4[bi + 6];
        }
        if (nmB) {
          int bi = (jB >> 1) + half;
          pb0 = cw4[bi]; pb1 = cw4[bi + 2]; pb2 = cw4[bi + 4]; pb3 = cw4[bi + 6];
        }
        if (mA) {
          float w0 = __int_as_float(qa0.y), w1 = __int_as_float(qa0.w);
          float w2 = __int_as_float(qa1.y), w3 = __int_as_float(qa1.w);
          float w4 = __int_as_float(qa2.y), w5 = __int_as_float(qa2.w);
          float w6 = __int_as_float(qa3.y), w7 = __int_as_float(qa3.w);
          aloA = fmaf(w0, bflo(gA0), aloA); ahiA = fmaf(w0, bfhi(gA0), ahiA);
          aloA = fmaf(w1, bflo(gA1), aloA); ahiA = fmaf(w1, bfhi(gA1), ahiA);
          aloA = fmaf(w2, bflo(gA2), aloA); ahiA = fmaf(w2, bfhi(gA2), ahiA);
          aloA = fmaf(w3, bflo(gA3), aloA); ahiA = fmaf(w3, bfhi(gA3), ahiA);
          aloA = fmaf(w4, bflo(gA4), aloA); ahiA = fmaf(w4, bfhi(gA4), ahiA);
          aloA = fmaf(w5, bflo(gA5), aloA); ahiA = fmaf(w5, bfhi(gA5), ahiA);
          aloA = fmaf(w6, bflo(gA6), aloA); ahiA = fmaf(w6, bfhi(gA6), ahiA);
          aloA = fmaf(w7, bflo(gA7), aloA); ahiA = fmaf(w7, bfhi(gA7), ahiA);
        }
        if (mB) {
          float w0 = __int_as_float(qb0.y), w1 = __int_as_float(qb0.w);
          float w2 = __int_as_float(qb1.y), w3 = __int_as_float(qb1.w);
          float w4 = __int_as_float(qb2.y), w5 = __int_as_float(qb2.w);
          float w6 = __int_as_float(qb3.y), w7 = __int_as_float(qb3.w);
          aloB = fmaf(w0, bflo(gB0), aloB); ahiB = fmaf(w0, bfhi(gB0), ahiB);
          aloB = fmaf(w1, bflo(gB1), aloB); ahiB = fmaf(w1, bfhi(gB1), ahiB);
          aloB = fmaf(w2, bflo(gB2), aloB); ahiB = fmaf(w2, bfhi(gB2), ahiB);
          aloB = fmaf(w3, bflo(gB3), aloB); ahiB = fmaf(w3, bfhi(gB3), ahiB);
          aloB = fmaf(w4, bflo(gB4), aloB); ahiB = fmaf(w4, bfhi(gB4), ahiB);
          aloB = fmaf(w5, bflo(gB5), aloB); ahiB = fmaf(w5, bfhi(gB5), ahiB);
          aloB = fmaf(w6, bflo(gB6), aloB); ahiB = fmaf(w6, bfhi(gB6), ahiB);
          aloB = fmaf(w7, bflo(gB7), aloB); ahiB = fmaf(w7, bfhi(gB7), ahiB);
        }
        if (nmA) { qa0 = pa0; qa1 = pa1; qa2 = pa2; qa3 = pa3; jA += 16; }
        if (nmB) { qb0 = pb0; qb1 = pb1; qb2 = pb2; qb3 = pb3; jB += 16; }
        mA = nmA; mB = nmB;
      }
      // merge halves and write sup rows
      aloA += __shfl_xor(aloA, 32);
      ahiA += __shfl_xor(ahiA, 32);
      unsigned h0pA = *(const unsigned*)(h0bf + (size_t)nA * HD + 2 * l31);
      float sloA = 0.9f * aloA + 0.1f * bflo(h0pA);
      float shiA = 0.9f * ahiA + 0.1f * bfhi(h0pA);
      if (half == 0)
        *(unsigned*)&sup[rwA][2 * l31] = ((unsigned)f2bf(shiA) << 16) | (unsigned)f2bf(sloA);
      if (nB < N) {
        aloB += __shfl_xor(aloB, 32);
        ahiB += __shfl_xor(ahiB, 32);
        unsigned h0pB = *(const unsigned*)(h0bf + (size_t)nB * HD + 2 * l31);
        float sloB = 0.9f * aloB + 0.1f * bflo(h0pB);
        float shiB = 0.9f * ahiB + 0.1f * bfhi(h0pB);
        if (half == 0)
          *(unsigned*)&sup[rwB][2 * l31] = ((unsigned)f2bf(shiB) << 16) | (unsigned)f2bf(sloB);
      } else if (half == 0) {
        *(unsigned*)&sup[rwB][2 * l31] = 0u;
      }
    } else if (half == 0) {
      *(unsigned*)&sup[rwA][2 * l31] = 0u;
      *(unsigned*)&sup[rwB][2 * l31] = 0u;
    }
  }
  __syncthreads();
  // matvec: out = relu(sup @ M) via MFMA
  {
    int rt = wv >> 1, cp = (wv & 1) * 2;
    int c15 = t & 15, g4i = t >> 4;
    const short8v a0 = *(const short8v*)&sup[rt * 16 + c15][g4i * 8];
    const short8v a1 = *(const short8v*)&sup[rt * 16 + c15][32 + g4i * 8];
#pragma unroll
    for (int q = 0; q < 2; ++q) {
      int ct = cp + q;
      const short8v b0 = *(const short8v*)&mfrag[ct * 64 + t][0];
      const short8v b1 = *(const short8v*)&mfrag[256 + ct * 64 + t][0];
      float4v acc = (float4v){0.f, 0.f, 0.f, 0.f};
      acc = __builtin_amdgcn_mfma_f32_16x16x32_bf16(a0, b0, acc, 0, 0, 0);
      acc = __builtin_amdgcn_mfma_f32_16x16x32_bf16(a1, b1, acc, 0, 0, 0);
#pragma unroll
      for (int r = 0; r < 4; ++r) {
        int row = rt * 16 + g4i * 4 + r;
        outt[row][ct * 16 + c15] = f2bf(fmaxf(acc[r], 0.f));
      }
    }
  }
  __syncthreads();
  {
    int row = tid >> 3, c0 = (tid & 7) * 8;
    int n = n0 + row;
    if (n < N) *(short8v*)&hout[(size_t)n * HD + c0] = *(const short8v*)&outt[row][c0];
  }
}

// ---------------- group table: g -> (m, l0) ----------------
__global__ __launch_bounds__(512) void k_gtab(int2* __restrict__ gtab) {
  int g = threadIdx.x;
  if (g >= NGRP) return;
  int m = 64, l0 = 65;
  if (g < 297) {
    int cum = 0;
    for (int mm = 0; mm < 65; ++mm) {
      int ng = (65 - mm + 7) >> 3;
      if (g < cum + ng) { m = mm; l0 = mm + (g - cum) * 8; break; }
      cum += ng;
    }
  }
  gtab[g] = make_int2(m, l0);
}

// ---------------- T[r,o] = Wo_o @ V_r^T  (+ linear/const bias terms) ----------------
__global__ __launch_bounds__(256) void k_T(const float* __restrict__ W_out, const float* __restrict__ V_W,
                                           const float* __restrict__ V_b, const float* __restrict__ U_W,
                                           const float* __restrict__ U_b,
                                           float* __restrict__ Tbuf, float* linbuf, float* cbuf) {
  int o = blockIdx.x % NOUT;
  int r = blockIdx.x / NOUT;
  __shared__ float Wo[64][65];
  __shared__ float Vs[64][65];
  __shared__ float t1[64], t2[64];
  int tid = threadIdx.x;
  int tx = tid & 15, ty = tid >> 4;
  for (int idx = tid; idx < 4096; idx += 256) {
    int m = idx >> 6, l = idx & 63;
    Wo[m][l] = W_out[(size_t)idx * NOUT + o];
    Vs[m][l] = V_W[(size_t)(r * 64 + m) * 64 + l];
  }
  __syncthreads();
  float acc[4][4] = {};
  for (int l = 0; l < 64; ++l) {
    float av[4], bv[4];
#pragma unroll
    for (int i = 0; i < 4; ++i) av[i] = Wo[ty * 4 + i][l];
#pragma unroll
    for (int j = 0; j < 4; ++j) bv[j] = Vs[tx * 4 + j][l];
#pragma unroll
    for (int i = 0; i < 4; ++i)
#pragma unroll
      for (int j = 0; j < 4; ++j) acc[i][j] = fmaf(av[i], bv[j], acc[i][j]);
  }
#pragma unroll
  for (int i = 0; i < 4; ++i)
#pragma unroll
    for (int j = 0; j < 4; ++j)
      Tbuf[(((size_t)r * NOUT + o) * 64 + ty * 4 + i) * 64 + tx * 4 + j] = acc[i][j];
  if (tid < 64) {
    float s1 = 0.f, s2 = 0.f;
    for (int l = 0; l < 64; ++l) s1 = fmaf(Wo[tid][l], V_b[r * 64 + l], s1);
    for (int m = 0; m < 64; ++m) s2 = fmaf(Wo[m][tid], U_b[r * 64 + m], s2);
    t1[tid] = s1;
    t2[tid] = s2;
  }
  __syncthreads();
  if (tid < 64) {
    float s = 0.f, s2 = 0.f;
    for (int m = 0; m < 64; ++m) s = fmaf(U_W[(size_t)(r * 64 + tid) * 64 + m], t1[m], s);
    for (int l = 0; l < 64; ++l) s2 = fmaf(Vs[tid][l], t2[l], s2);
    atomicAdd(&linbuf[o * 64 + tid], s + s2);
  }
  if (tid == 0) {
    float s = 0.f;
    for (int m = 0; m < 64; ++m) s = fmaf(U_b[r * 64 + m], t1[m], s);
    atomicAdd(&cbuf[o], s);
  }
}

// ---------------- Q_o = sum_r U_r @ T[r,o]; pack bf16 B-fragments ----------------
__global__ __launch_bounds__(256) void k_Q(const float* __restrict__ U_W, const float* __restrict__ Tbuf,
                                           const float* __restrict__ linbuf, const float* __restrict__ cbuf,
                                           const float* __restrict__ b_out,
                                           const int2* __restrict__ gtab, ushort* __restrict__ Bfrag) {
  int o = blockIdx.x;
  __shared__ float Us[64][65];
  __shared__ float Tb[64][65];
  __shared__ float Q[64][65];
  int tid = threadIdx.x, tx = tid & 15, ty = tid >> 4;
  float acc[4][4] = {};
  for (int r = 0; r < NRANK; ++r) {
    for (int idx = tid; idx < 4096; idx += 256) {
      int a = idx >> 6, mm = idx & 63;
      Us[a][mm] = U_W[(size_t)(r * 64 + a) * 64 + mm];
      Tb[a][mm] = Tbuf[(((size_t)r * NOUT + o) * 64 + a) * 64 + mm];
    }
    __syncthreads();
    for (int mm = 0; mm < 64; ++mm) {
      float av[4], bv[4];
#pragma unroll
      for (int i = 0; i < 4; ++i) av[i] = Us[ty * 4 + i][mm];
#pragma unroll
      for (int j = 0; j < 4; ++j) bv[j] = Tb[mm][tx * 4 + j];
#pragma unroll
      for (int i = 0; i < 4; ++i)
#pragma unroll
        for (int j = 0; j < 4; ++j) acc[i][j] = fmaf(av[i], bv[j], acc[i][j]);
    }
    __syncthreads();
  }
#pragma unroll
  for (int i = 0; i < 4; ++i)
#pragma unroll
    for (int j = 0; j < 4; ++j) Q[ty * 4 + i][tx * 4 + j] = acc[i][j];
  __syncthreads();
  int ot = o >> 4, o15 = o & 15;
  for (int idx = tid; idx < NGRP * 8; idx += 256) {
    int g = idx >> 3, e = idx & 7;
    int2 ml = gtab[g];
    int m = ml.x, l = ml.y + e;
    float v;
    if (l < 64) v = (m == l) ? Q[m][m] : Q[m][l] + Q[l][m];
    else if (l == 64) v = (m == 64) ? (cbuf[o] + b_out[o]) : linbuf[o * 64 + m];
    else v = 0.f;
    int c = g >> 2, g4 = g & 3;
    Bfrag[((((size_t)c * 3 + ot) * 64) + g4 * 16 + o15) * 8 + e] = f2bf(v);
  }
}

// ---------------- logits via MFMA + fused expmap0/proj/log_softmax ----------------
__global__ __launch_bounds__(256) void k_logits(const ushort* __restrict__ hbf,
                                                const ushort* __restrict__ Bfrag,
                                                const int2* __restrict__ gtab,
                                                float* __restrict__ out, int N) {
  __shared__ float eh[128][77];
  __shared__ int2 gs[NGRP];
  int tid = threadIdx.x;
  int n0 = blockIdx.x * 128;
  for (int idx = tid; idx < 128 * 16; idx += 256) {
    int n = idx >> 4, f4 = (idx & 15) << 2;
    int gn = n0 + n;
    float v0 = 0.f, v1 = 0.f, v2 = 0.f, v3 = 0.f;
    if (gn < N) {
      ushort4 u = *(const ushort4*)&hbf[(size_t)gn * HD + f4];
      v0 = bf2f(u.x); v1 = bf2f(u.y); v2 = bf2f(u.z); v3 = bf2f(u.w);
    }
    eh[n][f4] = v0; eh[n][f4 + 1] = v1; eh[n][f4 + 2] = v2; eh[n][f4 + 3] = v3;
  }
  for (int idx = tid; idx < 128 * 13; idx += 256) {
    int n = idx / 13, j = idx - n * 13;
    eh[n][64 + j] = (j == 0) ? 1.f : 0.f;
  }
  for (int idx = tid; idx < NGRP; idx += 256) gs[idx] = gtab[idx];
  __syncthreads();

  int w = tid >> 6, lane = tid & 63;
  int g4 = lane >> 4, c15 = lane & 15;
  float4v acc[2][3];
#pragma unroll
  for (int t = 0; t < 2; ++t)
#pragma unroll
    for (int ot = 0; ot < 3; ++ot) acc[t][ot] = (float4v){0.f, 0.f, 0.f, 0.f};
  const float* ehr0 = &eh[(w * 2 + 0) * 16 + c15][0];
  const float* ehr1 = &eh[(w * 2 + 1) * 16 + c15][0];

  for (int c = 0; c < NCHUNK; ++c) {
    const short8v b0 = *(const short8v*)&Bfrag[(((size_t)c * 3 + 0) * 64 + lane) * 8];
    const short8v b1 = *(const short8v*)&Bfrag[(((size_t)c * 3 + 1) * 64 + lane) * 8];
    const short8v b2 = *(const short8v*)&Bfrag[(((size_t)c * 3 + 2) * 64 + lane) * 8];
    int2 ml = gs[c * 4 + g4];
    int m = ml.x, l0 = ml.y;
    float hm0 = ehr0[m], hm1 = ehr1[m];
    short8v a0, a1;
#pragma unroll
    for (int e = 0; e < 8; ++e) {
      a0[e] = (short)f2bf(hm0 * ehr0[l0 + e]);
      a1[e] = (short)f2bf(hm1 * ehr1[l0 + e]);
    }
    acc[0][0] = __builtin_amdgcn_mfma_f32_16x16x32_bf16(a0, b0, acc[0][0], 0, 0, 0);
    acc[1][0] = __builtin_amdgcn_mfma_f32_16x16x32_bf16(a1, b0, acc[1][0], 0, 0, 0);
    acc[0][1] = __builtin_amdgcn_mfma_f32_16x16x32_bf16(a0, b1, acc[0][1], 0, 0, 0);
    acc[1][1] = __builtin_amdgcn_mfma_f32_16x16x32_bf16(a1, b1, acc[1][1], 0, 0, 0);
    acc[0][2] = __builtin_amdgcn_mfma_f32_16x16x32_bf16(a0, b2, acc[0][2], 0, 0, 0);
    acc[1][2] = __builtin_amdgcn_mfma_f32_16x16x32_bf16(a1, b2, acc[1][2], 0, 0, 0);
  }

  __syncthreads();  // all eh reads done; reuse as logits tile [128][41]
  float* ls = &eh[0][0];
#pragma unroll
  for (int t = 0; t < 2; ++t) {
    int rbase = (w * 2 + t) * 16 + g4 * 4;
#pragma unroll
    for (int ot = 0; ot < 3; ++ot) {
      int o = ot * 16 + c15;
      if (o < NOUT) {
#pragma unroll
        for (int r = 0; r < 4; ++r) ls[(rbase + r) * 41 + o] = acc[t][ot][r];
      }
    }
  }
  __syncthreads();
  if (tid < 128) {
    int n = n0 + tid;
    if (n < N) {
      float v[40];
      float s = 0.f;
#pragma unroll
      for (int i = 0; i < 40; ++i) { v[i] = ls[tid * 41 + i]; s = fmaf(v[i], v[i], s); }
      float un = fmaxf(sqrtf(s), 1e-15f);
      float sc = tanhf(un) / un;
      float s2 = 0.f;
#pragma unroll
      for (int i = 0; i < 40; ++i) { v[i] *= sc; s2 = fmaf(v[i], v[i], s2); }
      float ny = fmaxf(sqrtf(s2), 1e-15f);
      float maxn = 1.0f - 4e-3f;
      if (ny > maxn) {
        float f = maxn / ny;
#pragma unroll
        for (int i = 0; i < 40; ++i) v[i] *= f;
      }
      float vmax = v[0];
#pragma unroll
      for (int i = 1; i < 40; ++i) vmax = fmaxf(vmax, v[i]);
      float se = 0.f;
#pragma unroll
      for (int i = 0; i < 40; ++i) se += expf(v[i] - vmax);
      float lse = logf(se) + vmax;
      float4* q = (float4*)(out + (size_t)n * NOUT);
#pragma unroll
      for (int i = 0; i < 10; ++i) {
        float4 t;
        t.x = v[4 * i] - lse;
        t.y = v[4 * i + 1] - lse;
        t.z = v[4 * i + 2] - lse;
        t.w = v[4 * i + 3] - lse;
        q[i] = t;
      }
    }
  }
}

extern "C" void kernel_launch(void* const* d_in, const int* in_sizes, int n_in,
                              void* d_out, int out_size, void* d_ws, size_t ws_size,
                              hipStream_t stream) {
  const float* x = (const float*)d_in[0];
  const int* erow = (const int*)d_in[1];
  const int* ecol = (const int*)d_in[2];
  const float* ew = (const float*)d_in[3];
  const float* W_in = (const float*)d_in[4];
  const float* b_in = (const float*)d_in[5];
  const float* conv_W = (const float*)d_in[6];
  const float* U_W = (const float*)d_in[7];
  const float* U_b = (const float*)d_in[8];
  const float* V_W = (const float*)d_in[9];
  const float* V_b = (const float*)d_in[10];
  const float* W_out = (const float*)d_in[11];
  const float* b_out = (const float*)d_in[12];
  int N = in_sizes[0] / F_IN;
  int E = in_sizes[1];
  float* out = (float*)d_out;
  int EPAD = E + 16 * N;  // upper bound on padded edge count

  char* base = (char*)d_ws;
  size_t off = 0;
  auto alloc = [&](size_t bytes) -> void* {
    void* p = base + off;
    off += (bytes + 255) & ~(size_t)255;
    return p;
  };
  ushort* h0bf = (ushort*)alloc((size_t)N * HD * 2);
  ushort* hbfA = (ushort*)alloc((size_t)N * HD * 2);
  ushort* hbfB = (ushort*)alloc((size_t)N * HD * 2);
  int* rowptr = (int*)alloc((size_t)(N + 1) * 4);
  int* cursor = (int*)alloc((size_t)N * 4);
  int* counts = (int*)alloc((size_t)N * 4);
  int2* colw = (int2*)alloc((size_t)EPAD * 8);
  float* Tbuf = (float*)alloc((size_t)NRANK * NOUT * 64 * 64 * 4);
  ushort* Bfrag = (ushort*)alloc((size_t)NCHUNK * 3 * 64 * 8 * 2);
  ushort* Wbf = (ushort*)alloc((size_t)64 * 512 * 2);
  ushort* Mfrag = (ushort*)alloc((size_t)NL * 512 * 8 * 2);
  float* linbuf = (float*)alloc(NOUT * 64 * 4);
  float* cbuf = (float*)alloc(NOUT * 4);
  int2* gtab = (int2*)alloc(NGRP * 8);
  int* bsum = (int*)alloc(64 * 4);
  int* boff = (int*)alloc(64 * 4);

  int G = (N + 1023) / 1024;

  k_zero<<<(N + 255) / 256, 256, 0, stream>>>(counts, linbuf, cbuf, (ushort4*)Bfrag, colw, EPAD, N);
  k_count<<<(E + 255) / 256, 256, 0, stream>>>(erow, counts, E);
  k_scan1<<<G, 1024, 0, stream>>>(counts, rowptr, bsum, N);
  k_scan2<<<1, 64, 0, stream>>>(bsum, boff, G);
  k_scan3<<<G, 1024, 0, stream>>>(rowptr, cursor, boff, counts, N);
  k_fill<<<(E + 255) / 256, 256, 0, stream>>>(erow, ecol, ew, cursor, colw, E);
  k_wcvt<<<128, 256, 0, stream>>>(W_in, Wbf);
  k_gemm_in<<<(N + 15) / 16, 64, 0, stream>>>(x, Wbf, b_in, h0bf, N);
  k_mpack<<<NL, 256, 0, stream>>>(conv_W, Mfrag);
  k_gtab<<<1, 512, 0, stream>>>(gtab);
  k_T<<<NRANK * NOUT, 256, 0, stream>>>(W_out, V_W, V_b, U_W, U_b, Tbuf, linbuf, cbuf);
  k_Q<<<NOUT, 256, 0, stream>>>(U_W, Tbuf, linbuf, cbuf, b_out, gtab, Bfrag);

  const ushort* hin = h0bf;
  ushort* hout = hbfA;
  for (int l = 0; l < NL; ++l) {
    k_layer<<<(N + 31) / 32, 256, 0, stream>>>(hin, h0bf, rowptr, colw,
                                               Mfrag + (size_t)l * 512 * 8,
                                               hout, N);
    hin = hout;
    hout = (hout == hbfA) ? hbfB : hbfA;
  }
  k_logits<<<(N + 127) / 128, 256, 0, stream>>>(hin, Bfrag, gtab, out, N);
}

// Round 10
// 439.239 us; speedup vs baseline: 1.0884x; 1.0884x over previous
//
#include <hip/hip_runtime.h>
#include <cmath>

#define F_IN 500
#define HD 64
#define NL 8
#define NRANK 3
#define NOUT 40
#define NGRP 300   // 297 real (m,l0) groups of 8 + 3 zero pads -> K = 2400
#define NCHUNK 75  // 2400 / 32

typedef __attribute__((ext_vector_type(8))) short short8v;
typedef __attribute__((ext_vector_type(4))) float float4v;

__device__ __forceinline__ float bf2f(ushort u) {
  union { unsigned int i; float f; } v;
  v.i = ((unsigned int)u) << 16;
  return v.f;
}
__device__ __forceinline__ float bflo(unsigned int u) {
  union { unsigned int i; float f; } v;
  v.i = u << 16;
  return v.f;
}
__device__ __forceinline__ float bfhi(unsigned int u) {
  union { unsigned int i; float f; } v;
  v.i = u & 0xffff0000u;
  return v.f;
}
__device__ __forceinline__ ushort f2bf(float f) {
  union { float f; unsigned int i; } v;
  v.f = f;
  unsigned int b = v.i;
  return (ushort)((b + 0x7FFFu + ((b >> 16) & 1u)) >> 16);
}

// ---------------- zero init (counts, bias bufs, Bfrag, padded colw) ----------------
__global__ __launch_bounds__(256) void k_zero(int* counts, float* linbuf, float* cbuf,
                                              ushort4* bfrag4, int2* colw, int epad, int N) {
  int i = blockIdx.x * 256 + threadIdx.x;
  if (i < N) counts[i] = 0;
  if (i < NOUT * HD) linbuf[i] = 0.f;
  if (i < NOUT) cbuf[i] = 0.f;
  if (i < NCHUNK * 3 * 64 * 2) bfrag4[i] = make_ushort4(0, 0, 0, 0);
  for (int j = i; j < epad; j += gridDim.x * 256) colw[j] = make_int2(0, 0);
}

__global__ __launch_bounds__(256) void k_count(const int* __restrict__ row, int* counts, int E) {
  int e = blockIdx.x * 256 + threadIdx.x;
  if (e < E) atomicAdd(&counts[row[e]], 1);
}

// ---------------- parallel scan over degrees PADDED to 8 (3 kernels) ----------------
__global__ __launch_bounds__(1024) void k_scan1(const int* __restrict__ counts, int* __restrict__ rowptr,
                                                int* __restrict__ bsum, int N) {
  __shared__ int sh[1024];
  int t = threadIdx.x, i = blockIdx.x * 1024 + t;
  int c = (i < N) ? ((counts[i] + 7) & ~7) : 0;
  sh[t] = c;
  __syncthreads();
  for (int d = 1; d < 1024; d <<= 1) {
    int v = (t >= d) ? sh[t - d] : 0;
    __syncthreads();
    sh[t] += v;
    __syncthreads();
  }
  if (i < N) rowptr[i] = sh[t] - c;  // block-local exclusive
  if (t == 1023) bsum[blockIdx.x] = sh[1023];
}

__global__ __launch_bounds__(64) void k_scan2(const int* __restrict__ bsum, int* __restrict__ boff, int G) {
  int t = threadIdx.x;
  int base = 0;
  for (int s = 0; s < G; s += 64) {
    int i = s + t;
    int v = (i < G) ? bsum[i] : 0;
    int orig = v;
    for (int d = 1; d < 64; d <<= 1) {
      int u = __shfl_up(v, d, 64);
      if (t >= d) v += u;
    }
    if (i < G) boff[i] = base + v - orig;
    base += __shfl(v, 63, 64);
  }
}

__global__ __launch_bounds__(1024) void k_scan3(int* __restrict__ rowptr, int* __restrict__ cursor,
                                                const int* __restrict__ boff,
                                                const int* __restrict__ counts, int N) {
  int i = blockIdx.x * 1024 + threadIdx.x;
  if (i < N) {
    int v = rowptr[i] + boff[blockIdx.x];
    rowptr[i] = v;
    cursor[i] = v;
    if (i == N - 1) rowptr[N] = v + ((counts[i] + 7) & ~7);
  }
}

__global__ __launch_bounds__(256) void k_fill(const int* __restrict__ row, const int* __restrict__ col,
                                              const float* __restrict__ w, int* cursor,
                                              int2* __restrict__ colw, int E) {
  int e = blockIdx.x * 256 + threadIdx.x;
  if (e < E) {
    int r = row[e];
    int p = atomicAdd(&cursor[r], 1);
    colw[p] = make_int2(col[e] * HD, __float_as_int(w[e]));  // pre-scaled element offset
  }
}

// ---------------- W_in -> bf16 [64 cols][512 k], zero-padded ----------------
__global__ __launch_bounds__(256) void k_wcvt(const float* __restrict__ W, ushort* __restrict__ Wbf) {
  int i = blockIdx.x * 256 + threadIdx.x;
  if (i >= 64 * 512) return;
  int d = i >> 9, k = i & 511;
  Wbf[i] = (k < F_IN) ? f2bf(W[(size_t)k * HD + d]) : (ushort)0;
}

// ---------------- input GEMM via MFMA: Wbf in LDS (decouples lgkmcnt from x's vmcnt),
// depth-5 x register ring, 4 independent waves x 16 rows ----------------
__global__ __launch_bounds__(256) void k_gemm_in(const float* __restrict__ x,
                                                 const ushort* __restrict__ Wbf,
                                                 const float* __restrict__ b,
                                                 ushort* __restrict__ h0bf, int N) {
  __shared__ ushort wl[64][520];  // padded stride: 1040 B -> bank+4 per row, 2-way max
  int tid = threadIdx.x;
  int w = tid >> 6, lane = tid & 63;
  int c15 = lane & 15, g4 = lane >> 4;
  for (int i = tid; i < 4096; i += 256) {
    int d = i >> 6, k8 = (i & 63) << 3;
    *(short8v*)&wl[d][k8] = *(const short8v*)&Wbf[(d << 9) + k8];
  }
  __syncthreads();
  int rowA = blockIdx.x * 64 + w * 16 + c15;
  if (rowA >= N) rowA = N - 1;  // clamp; results discarded at store
  const float* xr = x + (size_t)rowA * F_IN;
  int koff = g4 * 8;
  float4v acc[4];
#pragma unroll
  for (int ct = 0; ct < 4; ++ct) acc[ct] = (float4v){0.f, 0.f, 0.f, 0.f};

  // depth-5 prefetch ring: 10 float4 x-loads outstanding; B comes from LDS only
  float4 pf[5][2];
#pragma unroll
  for (int i = 0; i < 5; ++i) {
    const float* p = xr + i * 32 + koff;
    pf[i][0] = *(const float4*)p;
    pf[i][1] = *(const float4*)(p + 4);
  }
#pragma unroll
  for (int kc = 0; kc < 15; ++kc) {
    float4 c0 = pf[kc % 5][0], c1 = pf[kc % 5][1];
    if (kc + 5 < 15) {
      const float* p = xr + (kc + 5) * 32 + koff;
      pf[kc % 5][0] = *(const float4*)p;
      pf[kc % 5][1] = *(const float4*)(p + 4);
    }
    short8v a;
    a[0] = (short)f2bf(c0.x); a[1] = (short)f2bf(c0.y);
    a[2] = (short)f2bf(c0.z); a[3] = (short)f2bf(c0.w);
    a[4] = (short)f2bf(c1.x); a[5] = (short)f2bf(c1.y);
    a[6] = (short)f2bf(c1.z); a[7] = (short)f2bf(c1.w);
    int kbase = kc * 32 + koff;
#pragma unroll
    for (int ct = 0; ct < 4; ++ct) {
      const short8v bb = *(const short8v*)&wl[ct * 16 + c15][kbase];
      acc[ct] = __builtin_amdgcn_mfma_f32_16x16x32_bf16(a, bb, acc[ct], 0, 0, 0);
    }
  }
  {  // chunk 15: floats 480..499 valid
    int kbase = 480 + koff;
    short8v a;
#pragma unroll
    for (int e = 0; e < 8; ++e) {
      int k = kbase + e;
      a[e] = (short)(k < F_IN ? f2bf(xr[k]) : (ushort)0);
    }
#pragma unroll
    for (int ct = 0; ct < 4; ++ct) {
      const short8v bb = *(const short8v*)&wl[ct * 16 + c15][kbase];
      acc[ct] = __builtin_amdgcn_mfma_f32_16x16x32_bf16(a, bb, acc[ct], 0, 0, 0);
    }
  }
  int mbase = blockIdx.x * 64 + w * 16 + g4 * 4;
#pragma unroll
  for (int ct = 0; ct < 4; ++ct) {
    int d = ct * 16 + c15;
    float bias = b[d];
#pragma unroll
    for (int r = 0; r < 4; ++r) {
      int m = mbase + r;
      if (m < N) {
        float v = acc[ct][r] + bias;
        h0bf[(size_t)m * HD + d] = f2bf(fmaxf(v, 0.f));
      }
    }
  }
}

// ---------------- per-layer matvec matrix in MFMA B-frag layout (once per layer) ----------------
__global__ __launch_bounds__(256) void k_mpack(const float* __restrict__ conv_W, ushort* __restrict__ Mfrag) {
  int l = blockIdx.x;
  const float* convW = conv_W + (size_t)l * HD * HD;
  ushort* out = Mfrag + (size_t)l * 512 * 8;
  float beta = logf(0.5f / (float)(l + 1) + 1.0f);
  int tid = threadIdx.x;
  for (int f = tid; f < 512; f += 256) {
    int kc = f >> 8, ct = (f >> 6) & 3, ln = f & 63;
    int kb = kc * 32 + ((ln >> 4) << 3);
    int col = (ct << 4) + (ln & 15);
    short8v vals;
#pragma unroll
    for (int e = 0; e < 8; ++e) {
      int k = kb + e;
      float v = beta * convW[(k << 6) + col] + ((k == col) ? (1.f - beta) : 0.f);
      vals[e] = (short)f2bf(v);
    }
    *(short8v*)&out[(size_t)f * 8] = vals;
  }
}

// ---------------- GCN2 layer: WIDE gathers (16B/lane, 8 edges/instr) + butterfly reduce
// + MFMA matvec, 32 rows/block ----------------
__global__ __launch_bounds__(256) void k_layer(const ushort* __restrict__ hin,
                                               const ushort* __restrict__ h0bf,
                                               const int* __restrict__ rowptrP, const int2* __restrict__ colw,
                                               const ushort* __restrict__ MfragL,
                                               ushort* __restrict__ hout, int N) {
  __shared__ ushort mfrag[512][8];
  __shared__ ushort sup[32][72];
  __shared__ ushort outt[32][72];
  int tid = threadIdx.x, wv = tid >> 6, t = tid & 63;
  {  // coalesced mfrag load (8 KB)
    const short8v* src = (const short8v*)MfragL;
    short8v* dst = (short8v*)&mfrag[0][0];
    dst[tid] = src[tid];
    dst[tid + 256] = src[tid + 256];
  }
  int n0 = blockIdx.x * 32;
  int re = 0;
  if (t < 9) {
    int nn = n0 + wv * 8 + t;
    if (nn <= N) re = rowptrP[nn];
  }
  int esl = t >> 3, sub = t & 7;  // edge slot 0..7, element octet 0..7
  const int2* cwe = colw + esl;
  const ushort* hsub = hin + sub * 8;
  for (int rr = 0; rr < 8; ++rr) {
    int rw = wv * 8 + rr, n = n0 + rw;
    if (n >= N) {
      if (t < 8) *(int4*)&sup[rw][t * 8] = make_int4(0, 0, 0, 0);
      continue;
    }
    int j = __shfl(re, rr, 64);
    int je = __shfl(re, rr + 1, 64);
    float a0 = 0.f, a1 = 0.f, a2 = 0.f, a3 = 0.f, a4 = 0.f, a5 = 0.f, a6 = 0.f, a7 = 0.f;
    if (j < je) {
      int2 q = cwe[j];
      j += 8;
      for (;;) {
        int2 qc = q;
        bool more = j < je;
        if (more) q = cwe[j];  // prefetch next edge descriptor while gather is in flight
        int4 g = *(const int4*)(hsub + (unsigned)qc.x);  // 16B = 8 bf16 of this edge's row
        float wgt = __int_as_float(qc.y);
        a0 = fmaf(wgt, bflo((unsigned)g.x), a0);
        a1 = fmaf(wgt, bfhi((unsigned)g.x), a1);
        a2 = fmaf(wgt, bflo((unsigned)g.y), a2);
        a3 = fmaf(wgt, bfhi((unsigned)g.y), a3);
        a4 = fmaf(wgt, bflo((unsigned)g.z), a4);
        a5 = fmaf(wgt, bfhi((unsigned)g.z), a5);
        a6 = fmaf(wgt, bflo((unsigned)g.w), a6);
        a7 = fmaf(wgt, bfhi((unsigned)g.w), a7);
        if (!more) break;
        j += 8;
      }
    }
    // butterfly reduce across the 8 edge slots (lanes at stride 8 share the same octet)
    a0 += __shfl_xor(a0, 8);  a1 += __shfl_xor(a1, 8);  a2 += __shfl_xor(a2, 8);  a3 += __shfl_xor(a3, 8);
    a4 += __shfl_xor(a4, 8);  a5 += __shfl_xor(a5, 8);  a6 += __shfl_xor(a6, 8);  a7 += __shfl_xor(a7, 8);
    a0 += __shfl_xor(a0, 16); a1 += __shfl_xor(a1, 16); a2 += __shfl_xor(a2, 16); a3 += __shfl_xor(a3, 16);
    a4 += __shfl_xor(a4, 16); a5 += __shfl_xor(a5, 16); a6 += __shfl_xor(a6, 16); a7 += __shfl_xor(a7, 16);
    a0 += __shfl_xor(a0, 32); a1 += __shfl_xor(a1, 32); a2 += __shfl_xor(a2, 32); a3 += __shfl_xor(a3, 32);
    a4 += __shfl_xor(a4, 32); a5 += __shfl_xor(a5, 32); a6 += __shfl_xor(a6, 32); a7 += __shfl_xor(a7, 32);
    if (t < 8) {
      int4 h0v = *(const int4*)(h0bf + (size_t)n * HD + t * 8);
      float s0 = 0.9f * a0 + 0.1f * bflo((unsigned)h0v.x);
      float s1 = 0.9f * a1 + 0.1f * bfhi((unsigned)h0v.x);
      float s2 = 0.9f * a2 + 0.1f * bflo((unsigned)h0v.y);
      float s3 = 0.9f * a3 + 0.1f * bfhi((unsigned)h0v.y);
      float s4 = 0.9f * a4 + 0.1f * bflo((unsigned)h0v.z);
      float s5 = 0.9f * a5 + 0.1f * bfhi((unsigned)h0v.z);
      float s6 = 0.9f * a6 + 0.1f * bflo((unsigned)h0v.w);
      float s7 = 0.9f * a7 + 0.1f * bfhi((unsigned)h0v.w);
      int4 p;
      p.x = (int)(((unsigned)f2bf(s1) << 16) | (unsigned)f2bf(s0));
      p.y = (int)(((unsigned)f2bf(s3) << 16) | (unsigned)f2bf(s2));
      p.z = (int)(((unsigned)f2bf(s5) << 16) | (unsigned)f2bf(s4));
      p.w = (int)(((unsigned)f2bf(s7) << 16) | (unsigned)f2bf(s6));
      *(int4*)&sup[rw][t * 8] = p;
    }
  }
  __syncthreads();
  // matvec: out = relu(sup @ M) via MFMA
  {
    int rt = wv >> 1, cp = (wv & 1) * 2;
    int c15 = t & 15, g4i = t >> 4;
    const short8v a0 = *(const short8v*)&sup[rt * 16 + c15][g4i * 8];
    const short8v a1 = *(const short8v*)&sup[rt * 16 + c15][32 + g4i * 8];
#pragma unroll
    for (int q = 0; q < 2; ++q) {
      int ct = cp + q;
      const short8v b0 = *(const short8v*)&mfrag[ct * 64 + t][0];
      const short8v b1 = *(const short8v*)&mfrag[256 + ct * 64 + t][0];
      float4v acc = (float4v){0.f, 0.f, 0.f, 0.f};
      acc = __builtin_amdgcn_mfma_f32_16x16x32_bf16(a0, b0, acc, 0, 0, 0);
      acc = __builtin_amdgcn_mfma_f32_16x16x32_bf16(a1, b1, acc, 0, 0, 0);
#pragma unroll
      for (int r = 0; r < 4; ++r) {
        int row = rt * 16 + g4i * 4 + r;
        outt[row][ct * 16 + c15] = f2bf(fmaxf(acc[r], 0.f));
      }
    }
  }
  __syncthreads();
  {
    int row = tid >> 3, c0 = (tid & 7) * 8;
    int n = n0 + row;
    if (n < N) *(short8v*)&hout[(size_t)n * HD + c0] = *(const short8v*)&outt[row][c0];
  }
}

// ---------------- group table: g -> (m, l0) ----------------
__global__ __launch_bounds__(512) void k_gtab(int2* __restrict__ gtab) {
  int g = threadIdx.x;
  if (g >= NGRP) return;
  int m = 64, l0 = 65;
  if (g < 297) {
    int cum = 0;
    for (int mm = 0; mm < 65; ++mm) {
      int ng = (65 - mm + 7) >> 3;
      if (g < cum + ng) { m = mm; l0 = mm + (g - cum) * 8; break; }
      cum += ng;
    }
  }
  gtab[g] = make_int2(m, l0);
}

// ---------------- T[r,o] = Wo_o @ V_r^T  (+ linear/const bias terms) ----------------
__global__ __launch_bounds__(256) void k_T(const float* __restrict__ W_out, const float* __restrict__ V_W,
                                           const float* __restrict__ V_b, const float* __restrict__ U_W,
                                           const float* __restrict__ U_b,
                                           float* __restrict__ Tbuf, float* linbuf, float* cbuf) {
  int o = blockIdx.x % NOUT;
  int r = blockIdx.x / NOUT;
  __shared__ float Wo[64][65];
  __shared__ float Vs[64][65];
  __shared__ float t1[64], t2[64];
  int tid = threadIdx.x;
  int tx = tid & 15, ty = tid >> 4;
  for (int idx = tid; idx < 4096; idx += 256) {
    int m = idx >> 6, l = idx & 63;
    Wo[m][l] = W_out[(size_t)idx * NOUT + o];
    Vs[m][l] = V_W[(size_t)(r * 64 + m) * 64 + l];
  }
  __syncthreads();
  float acc[4][4] = {};
  for (int l = 0; l < 64; ++l) {
    float av[4], bv[4];
#pragma unroll
    for (int i = 0; i < 4; ++i) av[i] = Wo[ty * 4 + i][l];
#pragma unroll
    for (int j = 0; j < 4; ++j) bv[j] = Vs[tx * 4 + j][l];
#pragma unroll
    for (int i = 0; i < 4; ++i)
#pragma unroll
      for (int j = 0; j < 4; ++j) acc[i][j] = fmaf(av[i], bv[j], acc[i][j]);
  }
#pragma unroll
  for (int i = 0; i < 4; ++i)
#pragma unroll
    for (int j = 0; j < 4; ++j)
      Tbuf[(((size_t)r * NOUT + o) * 64 + ty * 4 + i) * 64 + tx * 4 + j] = acc[i][j];
  if (tid < 64) {
    float s1 = 0.f, s2 = 0.f;
    for (int l = 0; l < 64; ++l) s1 = fmaf(Wo[tid][l], V_b[r * 64 + l], s1);
    for (int m = 0; m < 64; ++m) s2 = fmaf(Wo[m][tid], U_b[r * 64 + m], s2);
    t1[tid] = s1;
    t2[tid] = s2;
  }
  __syncthreads();
  if (tid < 64) {
    float s = 0.f, s2 = 0.f;
    for (int m = 0; m < 64; ++m) s = fmaf(U_W[(size_t)(r * 64 + tid) * 64 + m], t1[m], s);
    for (int l = 0; l < 64; ++l) s2 = fmaf(Vs[tid][l], t2[l], s2);
    atomicAdd(&linbuf[o * 64 + tid], s + s2);
  }
  if (tid == 0) {
    float s = 0.f;
    for (int m = 0; m < 64; ++m) s = fmaf(U_b[r * 64 + m], t1[m], s);
    atomicAdd(&cbuf[o], s);
  }
}

// ---------------- Q_o = sum_r U_r @ T[r,o]; pack bf16 B-fragments ----------------
__global__ __launch_bounds__(256) void k_Q(const float* __restrict__ U_W, const float* __restrict__ Tbuf,
                                           const float* __restrict__ linbuf, const float* __restrict__ cbuf,
                                           const float* __restrict__ b_out,
                                           const int2* __restrict__ gtab, ushort* __restrict__ Bfrag) {
  int o = blockIdx.x;
  __shared__ float Us[64][65];
  __shared__ float Tb[64][65];
  __shared__ float Q[64][65];
  int tid = threadIdx.x, tx = tid & 15, ty = tid >> 4;
  float acc[4][4] = {};
  for (int r = 0; r < NRANK; ++r) {
    for (int idx = tid; idx < 4096; idx += 256) {
      int a = idx >> 6, mm = idx & 63;
      Us[a][mm] = U_W[(size_t)(r * 64 + a) * 64 + mm];
      Tb[a][mm] = Tbuf[(((size_t)r * NOUT + o) * 64 + a) * 64 + mm];
    }
    __syncthreads();
    for (int mm = 0; mm < 64; ++mm) {
      float av[4], bv[4];
#pragma unroll
      for (int i = 0; i < 4; ++i) av[i] = Us[ty * 4 + i][mm];
#pragma unroll
      for (int j = 0; j < 4; ++j) bv[j] = Tb[mm][tx * 4 + j];
#pragma unroll
      for (int i = 0; i < 4; ++i)
#pragma unroll
        for (int j = 0; j < 4; ++j) acc[i][j] = fmaf(av[i], bv[j], acc[i][j]);
    }
    __syncthreads();
  }
#pragma unroll
  for (int i = 0; i < 4; ++i)
#pragma unroll
    for (int j = 0; j < 4; ++j) Q[ty * 4 + i][tx * 4 + j] = acc[i][j];
  __syncthreads();
  int ot = o >> 4, o15 = o & 15;
  for (int idx = tid; idx < NGRP * 8; idx += 256) {
    int g = idx >> 3, e = idx & 7;
    int2 ml = gtab[g];
    int m = ml.x, l = ml.y + e;
    float v;
    if (l < 64) v = (m == l) ? Q[m][m] : Q[m][l] + Q[l][m];
    else if (l == 64) v = (m == 64) ? (cbuf[o] + b_out[o]) : linbuf[o * 64 + m];
    else v = 0.f;
    int c = g >> 2, g4 = g & 3;
    Bfrag[((((size_t)c * 3 + ot) * 64) + g4 * 16 + o15) * 8 + e] = f2bf(v);
  }
}

// ---------------- logits via MFMA + fused expmap0/proj/log_softmax ----------------
__global__ __launch_bounds__(256) void k_logits(const ushort* __restrict__ hbf,
                                                const ushort* __restrict__ Bfrag,
                                                const int2* __restrict__ gtab,
                                                float* __restrict__ out, int N) {
  __shared__ float eh[128][77];
  __shared__ int2 gs[NGRP];
  int tid = threadIdx.x;
  int n0 = blockIdx.x * 128;
  for (int idx = tid; idx < 128 * 16; idx += 256) {
    int n = idx >> 4, f4 = (idx & 15) << 2;
    int gn = n0 + n;
    float v0 = 0.f, v1 = 0.f, v2 = 0.f, v3 = 0.f;
    if (gn < N) {
      ushort4 u = *(const ushort4*)&hbf[(size_t)gn * HD + f4];
      v0 = bf2f(u.x); v1 = bf2f(u.y); v2 = bf2f(u.z); v3 = bf2f(u.w);
    }
    eh[n][f4] = v0; eh[n][f4 + 1] = v1; eh[n][f4 + 2] = v2; eh[n][f4 + 3] = v3;
  }
  for (int idx = tid; idx < 128 * 13; idx += 256) {
    int n = idx / 13, j = idx - n * 13;
    eh[n][64 + j] = (j == 0) ? 1.f : 0.f;
  }
  for (int idx = tid; idx < NGRP; idx += 256) gs[idx] = gtab[idx];
  __syncthreads();

  int w = tid >> 6, lane = tid & 63;
  int g4 = lane >> 4, c15 = lane & 15;
  float4v acc[2][3];
#pragma unroll
  for (int t = 0; t < 2; ++t)
#pragma unroll
    for (int ot = 0; ot < 3; ++ot) acc[t][ot] = (float4v){0.f, 0.f, 0.f, 0.f};
  const float* ehr0 = &eh[(w * 2 + 0) * 16 + c15][0];
  const float* ehr1 = &eh[(w * 2 + 1) * 16 + c15][0];

  for (int c = 0; c < NCHUNK; ++c) {
    const short8v b0 = *(const short8v*)&Bfrag[(((size_t)c * 3 + 0) * 64 + lane) * 8];
    const short8v b1 = *(const short8v*)&Bfrag[(((size_t)c * 3 + 1) * 64 + lane) * 8];
    const short8v b2 = *(const short8v*)&Bfrag[(((size_t)c * 3 + 2) * 64 + lane) * 8];
    int2 ml = gs[c * 4 + g4];
    int m = ml.x, l0 = ml.y;
    float hm0 = ehr0[m], hm1 = ehr1[m];
    short8v a0, a1;
#pragma unroll
    for (int e = 0; e < 8; ++e) {
      a0[e] = (short)f2bf(hm0 * ehr0[l0 + e]);
      a1[e] = (short)f2bf(hm1 * ehr1[l0 + e]);
    }
    acc[0][0] = __builtin_amdgcn_mfma_f32_16x16x32_bf16(a0, b0, acc[0][0], 0, 0, 0);
    acc[1][0] = __builtin_amdgcn_mfma_f32_16x16x32_bf16(a1, b0, acc[1][0], 0, 0, 0);
    acc[0][1] = __builtin_amdgcn_mfma_f32_16x16x32_bf16(a0, b1, acc[0][1], 0, 0, 0);
    acc[1][1] = __builtin_amdgcn_mfma_f32_16x16x32_bf16(a1, b1, acc[1][1], 0, 0, 0);
    acc[0][2] = __builtin_amdgcn_mfma_f32_16x16x32_bf16(a0, b2, acc[0][2], 0, 0, 0);
    acc[1][2] = __builtin_amdgcn_mfma_f32_16x16x32_bf16(a1, b2, acc[1][2], 0, 0, 0);
  }

  __syncthreads();  // all eh reads done; reuse as logits tile [128][41]
  float* ls = &eh[0][0];
#pragma unroll
  for (int t = 0; t < 2; ++t) {
    int rbase = (w * 2 + t) * 16 + g4 * 4;
#pragma unroll
    for (int ot = 0; ot < 3; ++ot) {
      int o = ot * 16 + c15;
      if (o < NOUT) {
#pragma unroll
        for (int r = 0; r < 4; ++r) ls[(rbase + r) * 41 + o] = acc[t][ot][r];
      }
    }
  }
  __syncthreads();
  if (tid < 128) {
    int n = n0 + tid;
    if (n < N) {
      float v[40];
      float s = 0.f;
#pragma unroll
      for (int i = 0; i < 40; ++i) { v[i] = ls[tid * 41 + i]; s = fmaf(v[i], v[i], s); }
      float un = fmaxf(sqrtf(s), 1e-15f);
      float sc = tanhf(un) / un;
      float s2 = 0.f;
#pragma unroll
      for (int i = 0; i < 40; ++i) { v[i] *= sc; s2 = fmaf(v[i], v[i], s2); }
      float ny = fmaxf(sqrtf(s2), 1e-15f);
      float maxn = 1.0f - 4e-3f;
      if (ny > maxn) {
        float f = maxn / ny;
#pragma unroll
        for (int i = 0; i < 40; ++i) v[i] *= f;
      }
      float vmax = v[0];
#pragma unroll
      for (int i = 1; i < 40; ++i) vmax = fmaxf(vmax, v[i]);
      float se = 0.f;
#pragma unroll
      for (int i = 0; i < 40; ++i) se += expf(v[i] - vmax);
      float lse = logf(se) + vmax;
      float4* q = (float4*)(out + (size_t)n * NOUT);
#pragma unroll
      for (int i = 0; i < 10; ++i) {
        float4 t;
        t.x = v[4 * i] - lse;
        t.y = v[4 * i + 1] - lse;
        t.z = v[4 * i + 2] - lse;
        t.w = v[4 * i + 3] - lse;
        q[i] = t;
      }
    }
  }
}

extern "C" void kernel_launch(void* const* d_in, const int* in_sizes, int n_in,
                              void* d_out, int out_size, void* d_ws, size_t ws_size,
                              hipStream_t stream) {
  const float* x = (const float*)d_in[0];
  const int* erow = (const int*)d_in[1];
  const int* ecol = (const int*)d_in[2];
  const float* ew = (const float*)d_in[3];
  const float* W_in = (const float*)d_in[4];
  const float* b_in = (const float*)d_in[5];
  const float* conv_W = (const float*)d_in[6];
  const float* U_W = (const float*)d_in[7];
  const float* U_b = (const float*)d_in[8];
  const float* V_W = (const float*)d_in[9];
  const float* V_b = (const float*)d_in[10];
  const float* W_out = (const float*)d_in[11];
  const float* b_out = (const float*)d_in[12];
  int N = in_sizes[0] / F_IN;
  int E = in_sizes[1];
  float* out = (float*)d_out;
  int EPAD = E + 8 * N;  // upper bound on padded edge count

  char* base = (char*)d_ws;
  size_t off = 0;
  auto alloc = [&](size_t bytes) -> void* {
    void* p = base + off;
    off += (bytes + 255) & ~(size_t)255;
    return p;
  };
  ushort* h0bf = (ushort*)alloc((size_t)N * HD * 2);
  ushort* hbfA = (ushort*)alloc((size_t)N * HD * 2);
  ushort* hbfB = (ushort*)alloc((size_t)N * HD * 2);
  int* rowptr = (int*)alloc((size_t)(N + 1) * 4);
  int* cursor = (int*)alloc((size_t)N * 4);
  int* counts = (int*)alloc((size_t)N * 4);
  int2* colw = (int2*)alloc((size_t)EPAD * 8);
  float* Tbuf = (float*)alloc((size_t)NRANK * NOUT * 64 * 64 * 4);
  ushort* Bfrag = (ushort*)alloc((size_t)NCHUNK * 3 * 64 * 8 * 2);
  ushort* Wbf = (ushort*)alloc((size_t)64 * 512 * 2);
  ushort* Mfrag = (ushort*)alloc((size_t)NL * 512 * 8 * 2);
  float* linbuf = (float*)alloc(NOUT * 64 * 4);
  float* cbuf = (float*)alloc(NOUT * 4);
  int2* gtab = (int2*)alloc(NGRP * 8);
  int* bsum = (int*)alloc(64 * 4);
  int* boff = (int*)alloc(64 * 4);

  int G = (N + 1023) / 1024;

  k_zero<<<(N + 255) / 256, 256, 0, stream>>>(counts, linbuf, cbuf, (ushort4*)Bfrag, colw, EPAD, N);
  k_count<<<(E + 255) / 256, 256, 0, stream>>>(erow, counts, E);
  k_scan1<<<G, 1024, 0, stream>>>(counts, rowptr, bsum, N);
  k_scan2<<<1, 64, 0, stream>>>(bsum, boff, G);
  k_scan3<<<G, 1024, 0, stream>>>(rowptr, cursor, boff, counts, N);
  k_fill<<<(E + 255) / 256, 256, 0, stream>>>(erow, ecol, ew, cursor, colw, E);
  k_wcvt<<<128, 256, 0, stream>>>(W_in, Wbf);
  k_gemm_in<<<(N + 63) / 64, 256, 0, stream>>>(x, Wbf, b_in, h0bf, N);
  k_mpack<<<NL, 256, 0, stream>>>(conv_W, Mfrag);
  k_gtab<<<1, 512, 0, stream>>>(gtab);
  k_T<<<NRANK * NOUT, 256, 0, stream>>>(W_out, V_W, V_b, U_W, U_b, Tbuf, linbuf, cbuf);
  k_Q<<<NOUT, 256, 0, stream>>>(U_W, Tbuf, linbuf, cbuf, b_out, gtab, Bfrag);

  const ushort* hin = h0bf;
  ushort* hout = hbfA;
  for (int l = 0; l < NL; ++l) {
    k_layer<<<(N + 31) / 32, 256, 0, stream>>>(hin, h0bf, rowptr, colw,
                                               Mfrag + (size_t)l * 512 * 8,
                                               hout, N);
    hin = hout;
    hout = (hout == hbfA) ? hbfB : hbfA;
  }
  k_logits<<<(N + 127) / 128, 256, 0, stream>>>(hin, Bfrag, gtab, out, N);
}

// Round 11
// 399.070 us; speedup vs baseline: 1.1980x; 1.1007x over previous
//
#include <hip/hip_runtime.h>
#include <cmath>

#define F_IN 500
#define HD 64
#define NL 8
#define NRANK 3
#define NOUT 40
#define NGRP 300   // 297 real (m,l0) groups of 8 + 3 zero pads -> K = 2400
#define NCHUNK 75  // 2400 / 32

typedef __attribute__((ext_vector_type(8))) short short8v;
typedef __attribute__((ext_vector_type(4))) float float4v;

__device__ __forceinline__ float bf2f(ushort u) {
  union { unsigned int i; float f; } v;
  v.i = ((unsigned int)u) << 16;
  return v.f;
}
__device__ __forceinline__ float bflo(unsigned int u) {
  union { unsigned int i; float f; } v;
  v.i = u << 16;
  return v.f;
}
__device__ __forceinline__ float bfhi(unsigned int u) {
  union { unsigned int i; float f; } v;
  v.i = u & 0xffff0000u;
  return v.f;
}
__device__ __forceinline__ ushort f2bf(float f) {
  union { float f; unsigned int i; } v;
  v.f = f;
  unsigned int b = v.i;
  return (ushort)((b + 0x7FFFu + ((b >> 16) & 1u)) >> 16);
}

// ---------------- zero init (counts, bias bufs, Bfrag, padded colw) ----------------
__global__ __launch_bounds__(256) void k_zero(int* counts, float* linbuf, float* cbuf,
                                              ushort4* bfrag4, int2* colw, int epad, int N) {
  int i = blockIdx.x * 256 + threadIdx.x;
  if (i < N) counts[i] = 0;
  if (i < NOUT * HD) linbuf[i] = 0.f;
  if (i < NOUT) cbuf[i] = 0.f;
  if (i < NCHUNK * 3 * 64 * 2) bfrag4[i] = make_ushort4(0, 0, 0, 0);
  for (int j = i; j < epad; j += gridDim.x * 256) colw[j] = make_int2(0, 0);
}

__global__ __launch_bounds__(256) void k_count(const int* __restrict__ row, int* counts, int E) {
  int e = blockIdx.x * 256 + threadIdx.x;
  if (e < E) atomicAdd(&counts[row[e]], 1);
}

// ---------------- parallel scan over degrees PADDED to 8 (3 kernels) ----------------
__global__ __launch_bounds__(1024) void k_scan1(const int* __restrict__ counts, int* __restrict__ rowptr,
                                                int* __restrict__ bsum, int N) {
  __shared__ int sh[1024];
  int t = threadIdx.x, i = blockIdx.x * 1024 + t;
  int c = (i < N) ? ((counts[i] + 7) & ~7) : 0;
  sh[t] = c;
  __syncthreads();
  for (int d = 1; d < 1024; d <<= 1) {
    int v = (t >= d) ? sh[t - d] : 0;
    __syncthreads();
    sh[t] += v;
    __syncthreads();
  }
  if (i < N) rowptr[i] = sh[t] - c;  // block-local exclusive
  if (t == 1023) bsum[blockIdx.x] = sh[1023];
}

__global__ __launch_bounds__(64) void k_scan2(const int* __restrict__ bsum, int* __restrict__ boff, int G) {
  int t = threadIdx.x;
  int base = 0;
  for (int s = 0; s < G; s += 64) {
    int i = s + t;
    int v = (i < G) ? bsum[i] : 0;
    int orig = v;
    for (int d = 1; d < 64; d <<= 1) {
      int u = __shfl_up(v, d, 64);
      if (t >= d) v += u;
    }
    if (i < G) boff[i] = base + v - orig;
    base += __shfl(v, 63, 64);
  }
}

__global__ __launch_bounds__(1024) void k_scan3(int* __restrict__ rowptr, int* __restrict__ cursor,
                                                const int* __restrict__ boff,
                                                const int* __restrict__ counts, int N) {
  int i = blockIdx.x * 1024 + threadIdx.x;
  if (i < N) {
    int v = rowptr[i] + boff[blockIdx.x];
    rowptr[i] = v;
    cursor[i] = v;
    if (i == N - 1) rowptr[N] = v + ((counts[i] + 7) & ~7);
  }
}

__global__ __launch_bounds__(256) void k_fill(const int* __restrict__ row, const int* __restrict__ col,
                                              const float* __restrict__ w, int* cursor,
                                              int2* __restrict__ colw, int E) {
  int e = blockIdx.x * 256 + threadIdx.x;
  if (e < E) {
    int r = row[e];
    int p = atomicAdd(&cursor[r], 1);
    colw[p] = make_int2(col[e] * HD, __float_as_int(w[e]));  // pre-scaled element offset
  }
}

// ---------------- W_in -> bf16 [64 cols][512 k], zero-padded ----------------
__global__ __launch_bounds__(256) void k_wcvt(const float* __restrict__ W, ushort* __restrict__ Wbf) {
  int i = blockIdx.x * 256 + threadIdx.x;
  if (i >= 64 * 512) return;
  int d = i >> 9, k = i & 511;
  Wbf[i] = (k < F_IN) ? f2bf(W[(size_t)k * HD + d]) : (ushort)0;
}

// ---------------- x fp32 -> padded bf16 [N][512], pure streaming ----------------
__global__ __launch_bounds__(256) void k_xcvt(const float* __restrict__ x, ushort* __restrict__ xbf, int N) {
  int idx = blockIdx.x * 256 + threadIdx.x;  // one 8-element group per thread
  int total = N * 64;
  if (idx >= total) return;
  int row = idx >> 6, k8 = (idx & 63) << 3;
  short8v v;
  if (k8 <= 488) {
    const float4* p = (const float4*)(x + (size_t)row * F_IN + k8);
    float4 f0 = p[0], f1 = p[1];
    v[0] = (short)f2bf(f0.x); v[1] = (short)f2bf(f0.y);
    v[2] = (short)f2bf(f0.z); v[3] = (short)f2bf(f0.w);
    v[4] = (short)f2bf(f1.x); v[5] = (short)f2bf(f1.y);
    v[6] = (short)f2bf(f1.z); v[7] = (short)f2bf(f1.w);
  } else if (k8 == 496) {
    const float4* p = (const float4*)(x + (size_t)row * F_IN + 496);
    float4 f0 = p[0];
    v[0] = (short)f2bf(f0.x); v[1] = (short)f2bf(f0.y);
    v[2] = (short)f2bf(f0.z); v[3] = (short)f2bf(f0.w);
    v[4] = 0; v[5] = 0; v[6] = 0; v[7] = 0;
  } else {
    v = (short8v){0, 0, 0, 0, 0, 0, 0, 0};
  }
  *(short8v*)&xbf[((size_t)row << 9) + k8] = v;
}

// ---------------- input GEMM via MFMA from padded bf16 x, 1 wave / 16 rows ----------------
__global__ __launch_bounds__(64) void k_gemm_bf(const ushort* __restrict__ xbf,
                                                const ushort* __restrict__ Wbf,
                                                const float* __restrict__ b,
                                                ushort* __restrict__ h0bf, int N) {
  int lane = threadIdx.x;
  int c15 = lane & 15, g4 = lane >> 4;
  int rowA = blockIdx.x * 16 + c15;
  if (rowA >= N) rowA = N - 1;  // clamp; results discarded at store
  const ushort* xr = xbf + ((size_t)rowA << 9);
  int koff = g4 * 8;
  float4v acc[4];
#pragma unroll
  for (int ct = 0; ct < 4; ++ct) acc[ct] = (float4v){0.f, 0.f, 0.f, 0.f};
#pragma unroll
  for (int kc = 0; kc < 16; ++kc) {
    int kbase = kc * 32 + koff;
    const short8v a = *(const short8v*)(xr + kbase);
#pragma unroll
    for (int ct = 0; ct < 4; ++ct) {
      const short8v bb = *(const short8v*)&Wbf[((ct * 16 + c15) << 9) + kbase];
      acc[ct] = __builtin_amdgcn_mfma_f32_16x16x32_bf16(a, bb, acc[ct], 0, 0, 0);
    }
  }
  int mbase = blockIdx.x * 16 + g4 * 4;
#pragma unroll
  for (int ct = 0; ct < 4; ++ct) {
    int d = ct * 16 + c15;
    float bias = b[d];
#pragma unroll
    for (int r = 0; r < 4; ++r) {
      int m = mbase + r;
      if (m < N) {
        float v = acc[ct][r] + bias;
        h0bf[(size_t)m * HD + d] = f2bf(fmaxf(v, 0.f));
      }
    }
  }
}

// ---------------- per-layer matvec matrix in MFMA B-frag layout (once per layer) ----------------
__global__ __launch_bounds__(256) void k_mpack(const float* __restrict__ conv_W, ushort* __restrict__ Mfrag) {
  int l = blockIdx.x;
  const float* convW = conv_W + (size_t)l * HD * HD;
  ushort* out = Mfrag + (size_t)l * 512 * 8;
  float beta = logf(0.5f / (float)(l + 1) + 1.0f);
  int tid = threadIdx.x;
  for (int f = tid; f < 512; f += 256) {
    int kc = f >> 8, ct = (f >> 6) & 3, ln = f & 63;
    int kb = kc * 32 + ((ln >> 4) << 3);
    int col = (ct << 4) + (ln & 15);
    short8v vals;
#pragma unroll
    for (int e = 0; e < 8; ++e) {
      int k = kb + e;
      float v = beta * convW[(k << 6) + col] + ((k == col) ? (1.f - beta) : 0.f);
      vals[e] = (short)f2bf(v);
    }
    *(short8v*)&out[(size_t)f * 8] = vals;
  }
}

// ---------------- GCN2 layer: one row per 8-lane group, 8 edges/iter, no reduce ----------------
__global__ __launch_bounds__(256) void k_layer(const ushort* __restrict__ hin,
                                               const ushort* __restrict__ h0bf,
                                               const int* __restrict__ rowptrP, const int2* __restrict__ colw,
                                               const ushort* __restrict__ MfragL,
                                               ushort* __restrict__ hout, int N) {
  __shared__ ushort mfrag[512][8];
  __shared__ ushort sup[32][72];
  __shared__ ushort outt[32][72];
  int tid = threadIdx.x, wv = tid >> 6, t = tid & 63;
  {  // coalesced mfrag load (8 KB)
    const short8v* src = (const short8v*)MfragL;
    short8v* dst = (short8v*)&mfrag[0][0];
    dst[tid] = src[tid];
    dst[tid + 256] = src[tid + 256];
  }
  int n0 = blockIdx.x * 32;
  int re = 0;
  if (t < 9) {
    int nn = n0 + wv * 8 + t;
    if (nn <= N) re = rowptrP[nn];
  }
  int g = t >> 3, sub = t & 7;  // lane group = row slot, octet within row
  int rw = wv * 8 + g;
  int n = n0 + rw;
  int j = __shfl(re, g, 64);
  int je = __shfl(re, g + 1, 64);
  float a0 = 0.f, a1 = 0.f, a2 = 0.f, a3 = 0.f, a4 = 0.f, a5 = 0.f, a6 = 0.f, a7 = 0.f;
  const int4* cwp = (const int4*)colw;
  const ushort* hsub = hin + sub * 8;
  int jj = j;
  while (__any(jj < je)) {
    bool valid = jj < je;  // rows padded to 8 -> whole batch valid together
    int base = (valid ? jj : j) >> 1;
    int4 q0 = cwp[base], q1 = cwp[base + 1], q2 = cwp[base + 2], q3 = cwp[base + 3];
    // 8 wide gathers (16B each) for this row's next 8 edges, all in flight
    int4 g0 = *(const int4*)(hsub + (unsigned)q0.x);
    int4 g1 = *(const int4*)(hsub + (unsigned)q0.z);
    int4 g2 = *(const int4*)(hsub + (unsigned)q1.x);
    int4 g3 = *(const int4*)(hsub + (unsigned)q1.z);
    int4 g4_ = *(const int4*)(hsub + (unsigned)q2.x);
    int4 g5 = *(const int4*)(hsub + (unsigned)q2.z);
    int4 g6 = *(const int4*)(hsub + (unsigned)q3.x);
    int4 g7 = *(const int4*)(hsub + (unsigned)q3.z);
    float w0 = valid ? __int_as_float(q0.y) : 0.f;
    float w1 = valid ? __int_as_float(q0.w) : 0.f;
    float w2 = valid ? __int_as_float(q1.y) : 0.f;
    float w3 = valid ? __int_as_float(q1.w) : 0.f;
    float w4 = valid ? __int_as_float(q2.y) : 0.f;
    float w5 = valid ? __int_as_float(q2.w) : 0.f;
    float w6 = valid ? __int_as_float(q3.y) : 0.f;
    float w7 = valid ? __int_as_float(q3.w) : 0.f;
#define ACC8(gg, ww)                                        \
    a0 = fmaf(ww, bflo((unsigned)gg.x), a0);                \
    a1 = fmaf(ww, bfhi((unsigned)gg.x), a1);                \
    a2 = fmaf(ww, bflo((unsigned)gg.y), a2);                \
    a3 = fmaf(ww, bfhi((unsigned)gg.y), a3);                \
    a4 = fmaf(ww, bflo((unsigned)gg.z), a4);                \
    a5 = fmaf(ww, bfhi((unsigned)gg.z), a5);                \
    a6 = fmaf(ww, bflo((unsigned)gg.w), a6);                \
    a7 = fmaf(ww, bfhi((unsigned)gg.w), a7);
    ACC8(g0, w0) ACC8(g1, w1) ACC8(g2, w2) ACC8(g3, w3)
    ACC8(g4_, w4) ACC8(g5, w5) ACC8(g6, w6) ACC8(g7, w7)
#undef ACC8
    jj += 8;
  }
  {
    int4 h0v = (n < N) ? *(const int4*)(h0bf + (size_t)n * HD + sub * 8)
                       : make_int4(0, 0, 0, 0);
    float s0 = 0.9f * a0 + 0.1f * bflo((unsigned)h0v.x);
    float s1 = 0.9f * a1 + 0.1f * bfhi((unsigned)h0v.x);
    float s2 = 0.9f * a2 + 0.1f * bflo((unsigned)h0v.y);
    float s3 = 0.9f * a3 + 0.1f * bfhi((unsigned)h0v.y);
    float s4 = 0.9f * a4 + 0.1f * bflo((unsigned)h0v.z);
    float s5 = 0.9f * a5 + 0.1f * bfhi((unsigned)h0v.z);
    float s6 = 0.9f * a6 + 0.1f * bflo((unsigned)h0v.w);
    float s7 = 0.9f * a7 + 0.1f * bfhi((unsigned)h0v.w);
    int4 p;
    p.x = (int)(((unsigned)f2bf(s1) << 16) | (unsigned)f2bf(s0));
    p.y = (int)(((unsigned)f2bf(s3) << 16) | (unsigned)f2bf(s2));
    p.z = (int)(((unsigned)f2bf(s5) << 16) | (unsigned)f2bf(s4));
    p.w = (int)(((unsigned)f2bf(s7) << 16) | (unsigned)f2bf(s6));
    *(int4*)&sup[rw][sub * 8] = p;
  }
  __syncthreads();
  // matvec: out = relu(sup @ M) via MFMA
  {
    int rt = wv >> 1, cp = (wv & 1) * 2;
    int c15 = t & 15, g4i = t >> 4;
    const short8v a0v = *(const short8v*)&sup[rt * 16 + c15][g4i * 8];
    const short8v a1v = *(const short8v*)&sup[rt * 16 + c15][32 + g4i * 8];
#pragma unroll
    for (int q = 0; q < 2; ++q) {
      int ct = cp + q;
      const short8v b0 = *(const short8v*)&mfrag[ct * 64 + t][0];
      const short8v b1 = *(const short8v*)&mfrag[256 + ct * 64 + t][0];
      float4v acc = (float4v){0.f, 0.f, 0.f, 0.f};
      acc = __builtin_amdgcn_mfma_f32_16x16x32_bf16(a0v, b0, acc, 0, 0, 0);
      acc = __builtin_amdgcn_mfma_f32_16x16x32_bf16(a1v, b1, acc, 0, 0, 0);
#pragma unroll
      for (int r = 0; r < 4; ++r) {
        int row = rt * 16 + g4i * 4 + r;
        outt[row][ct * 16 + c15] = f2bf(fmaxf(acc[r], 0.f));
      }
    }
  }
  __syncthreads();
  {
    int row = tid >> 3, c0 = (tid & 7) * 8;
    int nn = n0 + row;
    if (nn < N) *(short8v*)&hout[(size_t)nn * HD + c0] = *(const short8v*)&outt[row][c0];
  }
}

// ---------------- group table: g -> (m, l0) ----------------
__global__ __launch_bounds__(512) void k_gtab(int2* __restrict__ gtab) {
  int g = threadIdx.x;
  if (g >= NGRP) return;
  int m = 64, l0 = 65;
  if (g < 297) {
    int cum = 0;
    for (int mm = 0; mm < 65; ++mm) {
      int ng = (65 - mm + 7) >> 3;
      if (g < cum + ng) { m = mm; l0 = mm + (g - cum) * 8; break; }
      cum += ng;
    }
  }
  gtab[g] = make_int2(m, l0);
}

// ---------------- T[r,o] = Wo_o @ V_r^T  (+ linear/const bias terms) ----------------
__global__ __launch_bounds__(256) void k_T(const float* __restrict__ W_out, const float* __restrict__ V_W,
                                           const float* __restrict__ V_b, const float* __restrict__ U_W,
                                           const float* __restrict__ U_b,
                                           float* __restrict__ Tbuf, float* linbuf, float* cbuf) {
  int o = blockIdx.x % NOUT;
  int r = blockIdx.x / NOUT;
  __shared__ float Wo[64][65];
  __shared__ float Vs[64][65];
  __shared__ float t1[64], t2[64];
  int tid = threadIdx.x;
  int tx = tid & 15, ty = tid >> 4;
  for (int idx = tid; idx < 4096; idx += 256) {
    int m = idx >> 6, l = idx & 63;
    Wo[m][l] = W_out[(size_t)idx * NOUT + o];
    Vs[m][l] = V_W[(size_t)(r * 64 + m) * 64 + l];
  }
  __syncthreads();
  float acc[4][4] = {};
  for (int l = 0; l < 64; ++l) {
    float av[4], bv[4];
#pragma unroll
    for (int i = 0; i < 4; ++i) av[i] = Wo[ty * 4 + i][l];
#pragma unroll
    for (int j = 0; j < 4; ++j) bv[j] = Vs[tx * 4 + j][l];
#pragma unroll
    for (int i = 0; i < 4; ++i)
#pragma unroll
      for (int j = 0; j < 4; ++j) acc[i][j] = fmaf(av[i], bv[j], acc[i][j]);
  }
#pragma unroll
  for (int i = 0; i < 4; ++i)
#pragma unroll
    for (int j = 0; j < 4; ++j)
      Tbuf[(((size_t)r * NOUT + o) * 64 + ty * 4 + i) * 64 + tx * 4 + j] = acc[i][j];
  if (tid < 64) {
    float s1 = 0.f, s2 = 0.f;
    for (int l = 0; l < 64; ++l) s1 = fmaf(Wo[tid][l], V_b[r * 64 + l], s1);
    for (int m = 0; m < 64; ++m) s2 = fmaf(Wo[m][tid], U_b[r * 64 + m], s2);
    t1[tid] = s1;
    t2[tid] = s2;
  }
  __syncthreads();
  if (tid < 64) {
    float s = 0.f, s2 = 0.f;
    for (int m = 0; m < 64; ++m) s = fmaf(U_W[(size_t)(r * 64 + tid) * 64 + m], t1[m], s);
    for (int l = 0; l < 64; ++l) s2 = fmaf(Vs[tid][l], t2[l], s2);
    atomicAdd(&linbuf[o * 64 + tid], s + s2);
  }
  if (tid == 0) {
    float s = 0.f;
    for (int m = 0; m < 64; ++m) s = fmaf(U_b[r * 64 + m], t1[m], s);
    atomicAdd(&cbuf[o], s);
  }
}

// ---------------- Q_o = sum_r U_r @ T[r,o]; pack bf16 B-fragments ----------------
__global__ __launch_bounds__(256) void k_Q(const float* __restrict__ U_W, const float* __restrict__ Tbuf,
                                           const float* __restrict__ linbuf, const float* __restrict__ cbuf,
                                           const float* __restrict__ b_out,
                                           const int2* __restrict__ gtab, ushort* __restrict__ Bfrag) {
  int o = blockIdx.x;
  __shared__ float Us[64][65];
  __shared__ float Tb[64][65];
  __shared__ float Q[64][65];
  int tid = threadIdx.x, tx = tid & 15, ty = tid >> 4;
  float acc[4][4] = {};
  for (int r = 0; r < NRANK; ++r) {
    for (int idx = tid; idx < 4096; idx += 256) {
      int a = idx >> 6, mm = idx & 63;
      Us[a][mm] = U_W[(size_t)(r * 64 + a) * 64 + mm];
      Tb[a][mm] = Tbuf[(((size_t)r * NOUT + o) * 64 + a) * 64 + mm];
    }
    __syncthreads();
    for (int mm = 0; mm < 64; ++mm) {
      float av[4], bv[4];
#pragma unroll
      for (int i = 0; i < 4; ++i) av[i] = Us[ty * 4 + i][mm];
#pragma unroll
      for (int j = 0; j < 4; ++j) bv[j] = Tb[mm][tx * 4 + j];
#pragma unroll
      for (int i = 0; i < 4; ++i)
#pragma unroll
        for (int j = 0; j < 4; ++j) acc[i][j] = fmaf(av[i], bv[j], acc[i][j]);
    }
    __syncthreads();
  }
#pragma unroll
  for (int i = 0; i < 4; ++i)
#pragma unroll
    for (int j = 0; j < 4; ++j) Q[ty * 4 + i][tx * 4 + j] = acc[i][j];
  __syncthreads();
  int ot = o >> 4, o15 = o & 15;
  for (int idx = tid; idx < NGRP * 8; idx += 256) {
    int g = idx >> 3, e = idx & 7;
    int2 ml = gtab[g];
    int m = ml.x, l = ml.y + e;
    float v;
    if (l < 64) v = (m == l) ? Q[m][m] : Q[m][l] + Q[l][m];
    else if (l == 64) v = (m == 64) ? (cbuf[o] + b_out[o]) : linbuf[o * 64 + m];
    else v = 0.f;
    int c = g >> 2, g4 = g & 3;
    Bfrag[((((size_t)c * 3 + ot) * 64) + g4 * 16 + o15) * 8 + e] = f2bf(v);
  }
}

// ---------------- logits via MFMA + fused expmap0/proj/log_softmax ----------------
__global__ __launch_bounds__(256) void k_logits(const ushort* __restrict__ hbf,
                                                const ushort* __restrict__ Bfrag,
                                                const int2* __restrict__ gtab,
                                                float* __restrict__ out, int N) {
  __shared__ float eh[128][77];
  __shared__ int2 gs[NGRP];
  int tid = threadIdx.x;
  int n0 = blockIdx.x * 128;
  for (int idx = tid; idx < 128 * 16; idx += 256) {
    int n = idx >> 4, f4 = (idx & 15) << 2;
    int gn = n0 + n;
    float v0 = 0.f, v1 = 0.f, v2 = 0.f, v3 = 0.f;
    if (gn < N) {
      ushort4 u = *(const ushort4*)&hbf[(size_t)gn * HD + f4];
      v0 = bf2f(u.x); v1 = bf2f(u.y); v2 = bf2f(u.z); v3 = bf2f(u.w);
    }
    eh[n][f4] = v0; eh[n][f4 + 1] = v1; eh[n][f4 + 2] = v2; eh[n][f4 + 3] = v3;
  }
  for (int idx = tid; idx < 128 * 13; idx += 256) {
    int n = idx / 13, j = idx - n * 13;
    eh[n][64 + j] = (j == 0) ? 1.f : 0.f;
  }
  for (int idx = tid; idx < NGRP; idx += 256) gs[idx] = gtab[idx];
  __syncthreads();

  int w = tid >> 6, lane = tid & 63;
  int g4 = lane >> 4, c15 = lane & 15;
  float4v acc[2][3];
#pragma unroll
  for (int t = 0; t < 2; ++t)
#pragma unroll
    for (int ot = 0; ot < 3; ++ot) acc[t][ot] = (float4v){0.f, 0.f, 0.f, 0.f};
  const float* ehr0 = &eh[(w * 2 + 0) * 16 + c15][0];
  const float* ehr1 = &eh[(w * 2 + 1) * 16 + c15][0];

  for (int c = 0; c < NCHUNK; ++c) {
    const short8v b0 = *(const short8v*)&Bfrag[(((size_t)c * 3 + 0) * 64 + lane) * 8];
    const short8v b1 = *(const short8v*)&Bfrag[(((size_t)c * 3 + 1) * 64 + lane) * 8];
    const short8v b2 = *(const short8v*)&Bfrag[(((size_t)c * 3 + 2) * 64 + lane) * 8];
    int2 ml = gs[c * 4 + g4];
    int m = ml.x, l0 = ml.y;
    float hm0 = ehr0[m], hm1 = ehr1[m];
    short8v a0, a1;
#pragma unroll
    for (int e = 0; e < 8; ++e) {
      a0[e] = (short)f2bf(hm0 * ehr0[l0 + e]);
      a1[e] = (short)f2bf(hm1 * ehr1[l0 + e]);
    }
    acc[0][0] = __builtin_amdgcn_mfma_f32_16x16x32_bf16(a0, b0, acc[0][0], 0, 0, 0);
    acc[1][0] = __builtin_amdgcn_mfma_f32_16x16x32_bf16(a1, b0, acc[1][0], 0, 0, 0);
    acc[0][1] = __builtin_amdgcn_mfma_f32_16x16x32_bf16(a0, b1, acc[0][1], 0, 0, 0);
    acc[1][1] = __builtin_amdgcn_mfma_f32_16x16x32_bf16(a1, b1, acc[1][1], 0, 0, 0);
    acc[0][2] = __builtin_amdgcn_mfma_f32_16x16x32_bf16(a0, b2, acc[0][2], 0, 0, 0);
    acc[1][2] = __builtin_amdgcn_mfma_f32_16x16x32_bf16(a1, b2, acc[1][2], 0, 0, 0);
  }

  __syncthreads();  // all eh reads done; reuse as logits tile [128][41]
  float* ls = &eh[0][0];
#pragma unroll
  for (int t = 0; t < 2; ++t) {
    int rbase = (w * 2 + t) * 16 + g4 * 4;
#pragma unroll
    for (int ot = 0; ot < 3; ++ot) {
      int o = ot * 16 + c15;
      if (o < NOUT) {
#pragma unroll
        for (int r = 0; r < 4; ++r) ls[(rbase + r) * 41 + o] = acc[t][ot][r];
      }
    }
  }
  __syncthreads();
  if (tid < 128) {
    int n = n0 + tid;
    if (n < N) {
      float v[40];
      float s = 0.f;
#pragma unroll
      for (int i = 0; i < 40; ++i) { v[i] = ls[tid * 41 + i]; s = fmaf(v[i], v[i], s); }
      float un = fmaxf(sqrtf(s), 1e-15f);
      float sc = tanhf(un) / un;
      float s2 = 0.f;
#pragma unroll
      for (int i = 0; i < 40; ++i) { v[i] *= sc; s2 = fmaf(v[i], v[i], s2); }
      float ny = fmaxf(sqrtf(s2), 1e-15f);
      float maxn = 1.0f - 4e-3f;
      if (ny > maxn) {
        float f = maxn / ny;
#pragma unroll
        for (int i = 0; i < 40; ++i) v[i] *= f;
      }
      float vmax = v[0];
#pragma unroll
      for (int i = 1; i < 40; ++i) vmax = fmaxf(vmax, v[i]);
      float se = 0.f;
#pragma unroll
      for (int i = 0; i < 40; ++i) se += expf(v[i] - vmax);
      float lse = logf(se) + vmax;
      float4* q = (float4*)(out + (size_t)n * NOUT);
#pragma unroll
      for (int i = 0; i < 10; ++i) {
        float4 t;
        t.x = v[4 * i] - lse;
        t.y = v[4 * i + 1] - lse;
        t.z = v[4 * i + 2] - lse;
        t.w = v[4 * i + 3] - lse;
        q[i] = t;
      }
    }
  }
}

extern "C" void kernel_launch(void* const* d_in, const int* in_sizes, int n_in,
                              void* d_out, int out_size, void* d_ws, size_t ws_size,
                              hipStream_t stream) {
  const float* x = (const float*)d_in[0];
  const int* erow = (const int*)d_in[1];
  const int* ecol = (const int*)d_in[2];
  const float* ew = (const float*)d_in[3];
  const float* W_in = (const float*)d_in[4];
  const float* b_in = (const float*)d_in[5];
  const float* conv_W = (const float*)d_in[6];
  const float* U_W = (const float*)d_in[7];
  const float* U_b = (const float*)d_in[8];
  const float* V_W = (const float*)d_in[9];
  const float* V_b = (const float*)d_in[10];
  const float* W_out = (const float*)d_in[11];
  const float* b_out = (const float*)d_in[12];
  int N = in_sizes[0] / F_IN;
  int E = in_sizes[1];
  float* out = (float*)d_out;
  int EPAD = E + 8 * N;  // upper bound on padded edge count

  char* base = (char*)d_ws;
  size_t off = 0;
  auto alloc = [&](size_t bytes) -> void* {
    void* p = base + off;
    off += (bytes + 255) & ~(size_t)255;
    return p;
  };
  ushort* h0bf = (ushort*)alloc((size_t)N * HD * 2);
  ushort* hbfA = (ushort*)alloc((size_t)N * HD * 2);
  ushort* hbfB = (ushort*)alloc((size_t)N * HD * 2);
  ushort* xbf = (ushort*)alloc((size_t)N * 512 * 2);
  int* rowptr = (int*)alloc((size_t)(N + 1) * 4);
  int* cursor = (int*)alloc((size_t)N * 4);
  int* counts = (int*)alloc((size_t)N * 4);
  int2* colw = (int2*)alloc((size_t)EPAD * 8);
  float* Tbuf = (float*)alloc((size_t)NRANK * NOUT * 64 * 64 * 4);
  ushort* Bfrag = (ushort*)alloc((size_t)NCHUNK * 3 * 64 * 8 * 2);
  ushort* Wbf = (ushort*)alloc((size_t)64 * 512 * 2);
  ushort* Mfrag = (ushort*)alloc((size_t)NL * 512 * 8 * 2);
  float* linbuf = (float*)alloc(NOUT * 64 * 4);
  float* cbuf = (float*)alloc(NOUT * 4);
  int2* gtab = (int2*)alloc(NGRP * 8);
  int* bsum = (int*)alloc(64 * 4);
  int* boff = (int*)alloc(64 * 4);

  int G = (N + 1023) / 1024;

  k_zero<<<(N + 255) / 256, 256, 0, stream>>>(counts, linbuf, cbuf, (ushort4*)Bfrag, colw, EPAD, N);
  k_count<<<(E + 255) / 256, 256, 0, stream>>>(erow, counts, E);
  k_scan1<<<G, 1024, 0, stream>>>(counts, rowptr, bsum, N);
  k_scan2<<<1, 64, 0, stream>>>(bsum, boff, G);
  k_scan3<<<G, 1024, 0, stream>>>(rowptr, cursor, boff, counts, N);
  k_fill<<<(E + 255) / 256, 256, 0, stream>>>(erow, ecol, ew, cursor, colw, E);
  k_wcvt<<<128, 256, 0, stream>>>(W_in, Wbf);
  k_xcvt<<<(N * 64 + 255) / 256, 256, 0, stream>>>(x, xbf, N);
  k_gemm_bf<<<(N + 15) / 16, 64, 0, stream>>>(xbf, Wbf, b_in, h0bf, N);
  k_mpack<<<NL, 256, 0, stream>>>(conv_W, Mfrag);
  k_gtab<<<1, 512, 0, stream>>>(gtab);
  k_T<<<NRANK * NOUT, 256, 0, stream>>>(W_out, V_W, V_b, U_W, U_b, Tbuf, linbuf, cbuf);
  k_Q<<<NOUT, 256, 0, stream>>>(U_W, Tbuf, linbuf, cbuf, b_out, gtab, Bfrag);

  const ushort* hin = h0bf;
  ushort* hout = hbfA;
  for (int l = 0; l < NL; ++l) {
    k_layer<<<(N + 31) / 32, 256, 0, stream>>>(hin, h0bf, rowptr, colw,
                                               Mfrag + (size_t)l * 512 * 8,
                                               hout, N);
    hin = hout;
    hout = (hout == hbfA) ? hbfB : hbfA;
  }
  k_logits<<<(N + 127) / 128, 256, 0, stream>>>(hin, Bfrag, gtab, out, N);
}

// Round 12
// 391.036 us; speedup vs baseline: 1.2226x; 1.0205x over previous
//
#include <hip/hip_runtime.h>
#include <cmath>

#define F_IN 500
#define HD 64
#define NL 8
#define NRANK 3
#define NOUT 40
#define NGRP 300   // 297 real (m,l0) groups of 8 + 3 zero pads -> K = 2400
#define NCHUNK 75  // 2400 / 32

typedef __attribute__((ext_vector_type(8))) short short8v;
typedef __attribute__((ext_vector_type(4))) float float4v;

__device__ __forceinline__ float bf2f(ushort u) {
  union { unsigned int i; float f; } v;
  v.i = ((unsigned int)u) << 16;
  return v.f;
}
__device__ __forceinline__ float bflo(unsigned int u) {
  union { unsigned int i; float f; } v;
  v.i = u << 16;
  return v.f;
}
__device__ __forceinline__ float bfhi(unsigned int u) {
  union { unsigned int i; float f; } v;
  v.i = u & 0xffff0000u;
  return v.f;
}
__device__ __forceinline__ ushort f2bf(float f) {
  union { float f; unsigned int i; } v;
  v.f = f;
  unsigned int b = v.i;
  return (ushort)((b + 0x7FFFu + ((b >> 16) & 1u)) >> 16);
}

// ---------------- zero init (counts, bias bufs, Bfrag, padded colw) ----------------
__global__ __launch_bounds__(256) void k_zero(int* counts, float* linbuf, float* cbuf,
                                              ushort4* bfrag4, int2* colw, int epad, int N) {
  int i = blockIdx.x * 256 + threadIdx.x;
  if (i < N) counts[i] = 0;
  if (i < NOUT * HD) linbuf[i] = 0.f;
  if (i < NOUT) cbuf[i] = 0.f;
  if (i < NCHUNK * 3 * 64 * 2) bfrag4[i] = make_ushort4(0, 0, 0, 0);
  if (i < epad) colw[i] = make_int2(0, 0);
}

__global__ __launch_bounds__(256) void k_count(const int* __restrict__ row, int* counts, int E) {
  int e = blockIdx.x * 256 + threadIdx.x;
  if (e < E) atomicAdd(&counts[row[e]], 1);
}

// ---------------- parallel scan over degrees PADDED to 8 (3 kernels) ----------------
__global__ __launch_bounds__(1024) void k_scan1(const int* __restrict__ counts, int* __restrict__ rowptr,
                                                int* __restrict__ bsum, int N) {
  __shared__ int sh[1024];
  int t = threadIdx.x, i = blockIdx.x * 1024 + t;
  int c = (i < N) ? ((counts[i] + 7) & ~7) : 0;
  sh[t] = c;
  __syncthreads();
  for (int d = 1; d < 1024; d <<= 1) {
    int v = (t >= d) ? sh[t - d] : 0;
    __syncthreads();
    sh[t] += v;
    __syncthreads();
  }
  if (i < N) rowptr[i] = sh[t] - c;  // block-local exclusive
  if (t == 1023) bsum[blockIdx.x] = sh[1023];
}

__global__ __launch_bounds__(64) void k_scan2(const int* __restrict__ bsum, int* __restrict__ boff, int G) {
  int t = threadIdx.x;
  int base = 0;
  for (int s = 0; s < G; s += 64) {
    int i = s + t;
    int v = (i < G) ? bsum[i] : 0;
    int orig = v;
    for (int d = 1; d < 64; d <<= 1) {
      int u = __shfl_up(v, d, 64);
      if (t >= d) v += u;
    }
    if (i < G) boff[i] = base + v - orig;
    base += __shfl(v, 63, 64);
  }
}

__global__ __launch_bounds__(1024) void k_scan3(int* __restrict__ rowptr, int* __restrict__ cursor,
                                                const int* __restrict__ boff,
                                                const int* __restrict__ counts, int N) {
  int i = blockIdx.x * 1024 + threadIdx.x;
  if (i < N) {
    int v = rowptr[i] + boff[blockIdx.x];
    rowptr[i] = v;
    cursor[i] = v;
    if (i == N - 1) rowptr[N] = v + ((counts[i] + 7) & ~7);
  }
}

__global__ __launch_bounds__(256) void k_fill(const int* __restrict__ row, const int* __restrict__ col,
                                              const float* __restrict__ w, int* cursor,
                                              int2* __restrict__ colw, int E) {
  int e = blockIdx.x * 256 + threadIdx.x;
  if (e < E) {
    int r = row[e];
    int p = atomicAdd(&cursor[r], 1);
    colw[p] = make_int2(col[e] * HD, __float_as_int(w[e]));  // pre-scaled element offset
  }
}

// ---------------- W_in -> bf16 [64 cols][512 k], zero-padded ----------------
__global__ __launch_bounds__(256) void k_wcvt(const float* __restrict__ W, ushort* __restrict__ Wbf) {
  int i = blockIdx.x * 256 + threadIdx.x;
  if (i >= 64 * 512) return;
  int d = i >> 9, k = i & 511;
  Wbf[i] = (k < F_IN) ? f2bf(W[(size_t)k * HD + d]) : (ushort)0;
}

// ---------------- x fp32 -> padded bf16 [N][512], pure streaming ----------------
__global__ __launch_bounds__(256) void k_xcvt(const float* __restrict__ x, ushort* __restrict__ xbf, int N) {
  int idx = blockIdx.x * 256 + threadIdx.x;  // one 8-element group per thread
  int total = N * 64;
  if (idx >= total) return;
  int row = idx >> 6, k8 = (idx & 63) << 3;
  short8v v;
  if (k8 <= 488) {
    const float4* p = (const float4*)(x + (size_t)row * F_IN + k8);
    float4 f0 = p[0], f1 = p[1];
    v[0] = (short)f2bf(f0.x); v[1] = (short)f2bf(f0.y);
    v[2] = (short)f2bf(f0.z); v[3] = (short)f2bf(f0.w);
    v[4] = (short)f2bf(f1.x); v[5] = (short)f2bf(f1.y);
    v[6] = (short)f2bf(f1.z); v[7] = (short)f2bf(f1.w);
  } else if (k8 == 496) {
    const float4* p = (const float4*)(x + (size_t)row * F_IN + 496);
    float4 f0 = p[0];
    v[0] = (short)f2bf(f0.x); v[1] = (short)f2bf(f0.y);
    v[2] = (short)f2bf(f0.z); v[3] = (short)f2bf(f0.w);
    v[4] = 0; v[5] = 0; v[6] = 0; v[7] = 0;
  } else {
    v = (short8v){0, 0, 0, 0, 0, 0, 0, 0};
  }
  *(short8v*)&xbf[((size_t)row << 9) + k8] = v;
}

// ---------------- input GEMM via MFMA from padded bf16 x, 1 wave / 16 rows ----------------
__global__ __launch_bounds__(64) void k_gemm_bf(const ushort* __restrict__ xbf,
                                                const ushort* __restrict__ Wbf,
                                                const float* __restrict__ b,
                                                ushort* __restrict__ h0bf, int N) {
  int lane = threadIdx.x;
  int c15 = lane & 15, g4 = lane >> 4;
  int rowA = blockIdx.x * 16 + c15;
  if (rowA >= N) rowA = N - 1;  // clamp; results discarded at store
  const ushort* xr = xbf + ((size_t)rowA << 9);
  int koff = g4 * 8;
  float4v acc[4];
#pragma unroll
  for (int ct = 0; ct < 4; ++ct) acc[ct] = (float4v){0.f, 0.f, 0.f, 0.f};
#pragma unroll
  for (int kc = 0; kc < 16; ++kc) {
    int kbase = kc * 32 + koff;
    const short8v a = *(const short8v*)(xr + kbase);
#pragma unroll
    for (int ct = 0; ct < 4; ++ct) {
      const short8v bb = *(const short8v*)&Wbf[((ct * 16 + c15) << 9) + kbase];
      acc[ct] = __builtin_amdgcn_mfma_f32_16x16x32_bf16(a, bb, acc[ct], 0, 0, 0);
    }
  }
  int mbase = blockIdx.x * 16 + g4 * 4;
#pragma unroll
  for (int ct = 0; ct < 4; ++ct) {
    int d = ct * 16 + c15;
    float bias = b[d];
#pragma unroll
    for (int r = 0; r < 4; ++r) {
      int m = mbase + r;
      if (m < N) {
        float v = acc[ct][r] + bias;
        h0bf[(size_t)m * HD + d] = f2bf(fmaxf(v, 0.f));
      }
    }
  }
}

// ---------------- per-layer matvec matrix in MFMA B-frag layout (once per layer) ----------------
__global__ __launch_bounds__(256) void k_mpack(const float* __restrict__ conv_W, ushort* __restrict__ Mfrag) {
  int l = blockIdx.x;
  const float* convW = conv_W + (size_t)l * HD * HD;
  ushort* out = Mfrag + (size_t)l * 512 * 8;
  float beta = logf(0.5f / (float)(l + 1) + 1.0f);
  int tid = threadIdx.x;
  for (int f = tid; f < 512; f += 256) {
    int kc = f >> 8, ct = (f >> 6) & 3, ln = f & 63;
    int kb = kc * 32 + ((ln >> 4) << 3);
    int col = (ct << 4) + (ln & 15);
    short8v vals;
#pragma unroll
    for (int e = 0; e < 8; ++e) {
      int k = kb + e;
      float v = beta * convW[(k << 6) + col] + ((k == col) ? (1.f - beta) : 0.f);
      vals[e] = (short)f2bf(v);
    }
    *(short8v*)&out[(size_t)f * 8] = vals;
  }
}

// ---------------- GCN2 layer: one row per 8-lane group, 8 edges/iter,
// next-batch DESCRIPTOR PREFETCH in flight with gathers, no cross-lane reduce ----------------
__global__ __launch_bounds__(256) void k_layer(const ushort* __restrict__ hin,
                                               const ushort* __restrict__ h0bf,
                                               const int* __restrict__ rowptrP, const int2* __restrict__ colw,
                                               const ushort* __restrict__ MfragL,
                                               ushort* __restrict__ hout, int N) {
  __shared__ ushort mfrag[512][8];
  __shared__ ushort sup[32][72];
  __shared__ ushort outt[32][72];
  int tid = threadIdx.x, wv = tid >> 6, t = tid & 63;
  {  // coalesced mfrag load (8 KB)
    const short8v* src = (const short8v*)MfragL;
    short8v* dst = (short8v*)&mfrag[0][0];
    dst[tid] = src[tid];
    dst[tid + 256] = src[tid + 256];
  }
  int n0 = blockIdx.x * 32;
  int re = 0;
  if (t < 9) {
    int nn = n0 + wv * 8 + t;
    if (nn <= N) re = rowptrP[nn];
  }
  int g = t >> 3, sub = t & 7;  // lane group = row slot, octet within row
  int rw = wv * 8 + g;
  int n = n0 + rw;
  int j = __shfl(re, g, 64);
  int je = __shfl(re, g + 1, 64);
  float a0 = 0.f, a1 = 0.f, a2 = 0.f, a3 = 0.f, a4 = 0.f, a5 = 0.f, a6 = 0.f, a7 = 0.f;
  const int4* cwp = (const int4*)colw;
  const ushort* hsub = hin + sub * 8;
  bool act = j < je;
  int4 z4 = make_int4(0, 0, 0, 0);
  int4 q0 = z4, q1 = z4, q2 = z4, q3 = z4;
  if (act) {
    int base = j >> 1;
    q0 = cwp[base]; q1 = cwp[base + 1]; q2 = cwp[base + 2]; q3 = cwp[base + 3];
  }
  while (__any(act)) {
    // 8 wide gathers (16B each) issued back-to-back
    int4 g0 = *(const int4*)(hsub + (unsigned)q0.x);
    int4 g1 = *(const int4*)(hsub + (unsigned)q0.z);
    int4 g2 = *(const int4*)(hsub + (unsigned)q1.x);
    int4 g3 = *(const int4*)(hsub + (unsigned)q1.z);
    int4 g4_ = *(const int4*)(hsub + (unsigned)q2.x);
    int4 g5 = *(const int4*)(hsub + (unsigned)q2.z);
    int4 g6 = *(const int4*)(hsub + (unsigned)q3.x);
    int4 g7 = *(const int4*)(hsub + (unsigned)q3.z);
    j += 8;
    bool nact = j < je;
    // next batch's descriptors prefetched WHILE gathers are in flight
    int4 p0 = q0, p1 = q1, p2 = q2, p3 = q3;
    if (nact) {
      int base = j >> 1;
      p0 = cwp[base]; p1 = cwp[base + 1]; p2 = cwp[base + 2]; p3 = cwp[base + 3];
    }
    float w0 = act ? __int_as_float(q0.y) : 0.f;
    float w1 = act ? __int_as_float(q0.w) : 0.f;
    float w2 = act ? __int_as_float(q1.y) : 0.f;
    float w3 = act ? __int_as_float(q1.w) : 0.f;
    float w4 = act ? __int_as_float(q2.y) : 0.f;
    float w5 = act ? __int_as_float(q2.w) : 0.f;
    float w6 = act ? __int_as_float(q3.y) : 0.f;
    float w7 = act ? __int_as_float(q3.w) : 0.f;
#define ACC8(gg, ww)                                        \
    a0 = fmaf(ww, bflo((unsigned)gg.x), a0);                \
    a1 = fmaf(ww, bfhi((unsigned)gg.x), a1);                \
    a2 = fmaf(ww, bflo((unsigned)gg.y), a2);                \
    a3 = fmaf(ww, bfhi((unsigned)gg.y), a3);                \
    a4 = fmaf(ww, bflo((unsigned)gg.z), a4);                \
    a5 = fmaf(ww, bfhi((unsigned)gg.z), a5);                \
    a6 = fmaf(ww, bflo((unsigned)gg.w), a6);                \
    a7 = fmaf(ww, bfhi((unsigned)gg.w), a7);
    ACC8(g0, w0) ACC8(g1, w1) ACC8(g2, w2) ACC8(g3, w3)
    ACC8(g4_, w4) ACC8(g5, w5) ACC8(g6, w6) ACC8(g7, w7)
#undef ACC8
    q0 = p0; q1 = p1; q2 = p2; q3 = p3;
    act = nact;
  }
  {
    int4 h0v = (n < N) ? *(const int4*)(h0bf + (size_t)n * HD + sub * 8)
                       : make_int4(0, 0, 0, 0);
    float s0 = 0.9f * a0 + 0.1f * bflo((unsigned)h0v.x);
    float s1 = 0.9f * a1 + 0.1f * bfhi((unsigned)h0v.x);
    float s2 = 0.9f * a2 + 0.1f * bflo((unsigned)h0v.y);
    float s3 = 0.9f * a3 + 0.1f * bfhi((unsigned)h0v.y);
    float s4 = 0.9f * a4 + 0.1f * bflo((unsigned)h0v.z);
    float s5 = 0.9f * a5 + 0.1f * bfhi((unsigned)h0v.z);
    float s6 = 0.9f * a6 + 0.1f * bflo((unsigned)h0v.w);
    float s7 = 0.9f * a7 + 0.1f * bfhi((unsigned)h0v.w);
    int4 p;
    p.x = (int)(((unsigned)f2bf(s1) << 16) | (unsigned)f2bf(s0));
    p.y = (int)(((unsigned)f2bf(s3) << 16) | (unsigned)f2bf(s2));
    p.z = (int)(((unsigned)f2bf(s5) << 16) | (unsigned)f2bf(s4));
    p.w = (int)(((unsigned)f2bf(s7) << 16) | (unsigned)f2bf(s6));
    *(int4*)&sup[rw][sub * 8] = p;
  }
  __syncthreads();
  // matvec: out = relu(sup @ M) via MFMA
  {
    int rt = wv >> 1, cp = (wv & 1) * 2;
    int c15 = t & 15, g4i = t >> 4;
    const short8v a0v = *(const short8v*)&sup[rt * 16 + c15][g4i * 8];
    const short8v a1v = *(const short8v*)&sup[rt * 16 + c15][32 + g4i * 8];
#pragma unroll
    for (int q = 0; q < 2; ++q) {
      int ct = cp + q;
      const short8v b0 = *(const short8v*)&mfrag[ct * 64 + t][0];
      const short8v b1 = *(const short8v*)&mfrag[256 + ct * 64 + t][0];
      float4v acc = (float4v){0.f, 0.f, 0.f, 0.f};
      acc = __builtin_amdgcn_mfma_f32_16x16x32_bf16(a0v, b0, acc, 0, 0, 0);
      acc = __builtin_amdgcn_mfma_f32_16x16x32_bf16(a1v, b1, acc, 0, 0, 0);
#pragma unroll
      for (int r = 0; r < 4; ++r) {
        int row = rt * 16 + g4i * 4 + r;
        outt[row][ct * 16 + c15] = f2bf(fmaxf(acc[r], 0.f));
      }
    }
  }
  __syncthreads();
  {
    int row = tid >> 3, c0 = (tid & 7) * 8;
    int nn = n0 + row;
    if (nn < N) *(short8v*)&hout[(size_t)nn * HD + c0] = *(const short8v*)&outt[row][c0];
  }
}

// ---------------- group table: g -> (m, l0) ----------------
__global__ __launch_bounds__(512) void k_gtab(int2* __restrict__ gtab) {
  int g = threadIdx.x;
  if (g >= NGRP) return;
  int m = 64, l0 = 65;
  if (g < 297) {
    int cum = 0;
    for (int mm = 0; mm < 65; ++mm) {
      int ng = (65 - mm + 7) >> 3;
      if (g < cum + ng) { m = mm; l0 = mm + (g - cum) * 8; break; }
      cum += ng;
    }
  }
  gtab[g] = make_int2(m, l0);
}

// ---------------- T[r,o] = Wo_o @ V_r^T  (+ linear/const bias terms) ----------------
__global__ __launch_bounds__(256) void k_T(const float* __restrict__ W_out, const float* __restrict__ V_W,
                                           const float* __restrict__ V_b, const float* __restrict__ U_W,
                                           const float* __restrict__ U_b,
                                           float* __restrict__ Tbuf, float* linbuf, float* cbuf) {
  int o = blockIdx.x % NOUT;
  int r = blockIdx.x / NOUT;
  __shared__ float Wo[64][65];
  __shared__ float Vs[64][65];
  __shared__ float t1[64], t2[64];
  int tid = threadIdx.x;
  int tx = tid & 15, ty = tid >> 4;
  for (int idx = tid; idx < 4096; idx += 256) {
    int m = idx >> 6, l = idx & 63;
    Wo[m][l] = W_out[(size_t)idx * NOUT + o];
    Vs[m][l] = V_W[(size_t)(r * 64 + m) * 64 + l];
  }
  __syncthreads();
  float acc[4][4] = {};
  for (int l = 0; l < 64; ++l) {
    float av[4], bv[4];
#pragma unroll
    for (int i = 0; i < 4; ++i) av[i] = Wo[ty * 4 + i][l];
#pragma unroll
    for (int j = 0; j < 4; ++j) bv[j] = Vs[tx * 4 + j][l];
#pragma unroll
    for (int i = 0; i < 4; ++i)
#pragma unroll
      for (int j = 0; j < 4; ++j) acc[i][j] = fmaf(av[i], bv[j], acc[i][j]);
  }
#pragma unroll
  for (int i = 0; i < 4; ++i)
#pragma unroll
    for (int j = 0; j < 4; ++j)
      Tbuf[(((size_t)r * NOUT + o) * 64 + ty * 4 + i) * 64 + tx * 4 + j] = acc[i][j];
  if (tid < 64) {
    float s1 = 0.f, s2 = 0.f;
    for (int l = 0; l < 64; ++l) s1 = fmaf(Wo[tid][l], V_b[r * 64 + l], s1);
    for (int m = 0; m < 64; ++m) s2 = fmaf(Wo[m][tid], U_b[r * 64 + m], s2);
    t1[tid] = s1;
    t2[tid] = s2;
  }
  __syncthreads();
  if (tid < 64) {
    float s = 0.f, s2 = 0.f;
    for (int m = 0; m < 64; ++m) s = fmaf(U_W[(size_t)(r * 64 + tid) * 64 + m], t1[m], s);
    for (int l = 0; l < 64; ++l) s2 = fmaf(Vs[tid][l], t2[l], s2);
    atomicAdd(&linbuf[o * 64 + tid], s + s2);
  }
  if (tid == 0) {
    float s = 0.f;
    for (int m = 0; m < 64; ++m) s = fmaf(U_b[r * 64 + m], t1[m], s);
    atomicAdd(&cbuf[o], s);
  }
}

// ---------------- Q_o = sum_r U_r @ T[r,o]; pack bf16 B-fragments ----------------
__global__ __launch_bounds__(256) void k_Q(const float* __restrict__ U_W, const float* __restrict__ Tbuf,
                                           const float* __restrict__ linbuf, const float* __restrict__ cbuf,
                                           const float* __restrict__ b_out,
                                           const int2* __restrict__ gtab, ushort* __restrict__ Bfrag) {
  int o = blockIdx.x;
  __shared__ float Us[64][65];
  __shared__ float Tb[64][65];
  __shared__ float Q[64][65];
  int tid = threadIdx.x, tx = tid & 15, ty = tid >> 4;
  float acc[4][4] = {};
  for (int r = 0; r < NRANK; ++r) {
    for (int idx = tid; idx < 4096; idx += 256) {
      int a = idx >> 6, mm = idx & 63;
      Us[a][mm] = U_W[(size_t)(r * 64 + a) * 64 + mm];
      Tb[a][mm] = Tbuf[(((size_t)r * NOUT + o) * 64 + a) * 64 + mm];
    }
    __syncthreads();
    for (int mm = 0; mm < 64; ++mm) {
      float av[4], bv[4];
#pragma unroll
      for (int i = 0; i < 4; ++i) av[i] = Us[ty * 4 + i][mm];
#pragma unroll
      for (int j = 0; j < 4; ++j) bv[j] = Tb[mm][tx * 4 + j];
#pragma unroll
      for (int i = 0; i < 4; ++i)
#pragma unroll
        for (int j = 0; j < 4; ++j) acc[i][j] = fmaf(av[i], bv[j], acc[i][j]);
    }
    __syncthreads();
  }
#pragma unroll
  for (int i = 0; i < 4; ++i)
#pragma unroll
    for (int j = 0; j < 4; ++j) Q[ty * 4 + i][tx * 4 + j] = acc[i][j];
  __syncthreads();
  int ot = o >> 4, o15 = o & 15;
  for (int idx = tid; idx < NGRP * 8; idx += 256) {
    int g = idx >> 3, e = idx & 7;
    int2 ml = gtab[g];
    int m = ml.x, l = ml.y + e;
    float v;
    if (l < 64) v = (m == l) ? Q[m][m] : Q[m][l] + Q[l][m];
    else if (l == 64) v = (m == 64) ? (cbuf[o] + b_out[o]) : linbuf[o * 64 + m];
    else v = 0.f;
    int c = g >> 2, g4 = g & 3;
    Bfrag[((((size_t)c * 3 + ot) * 64) + g4 * 16 + o15) * 8 + e] = f2bf(v);
  }
}

// ---------------- logits via MFMA + fused expmap0/proj/log_softmax ----------------
__global__ __launch_bounds__(256) void k_logits(const ushort* __restrict__ hbf,
                                                const ushort* __restrict__ Bfrag,
                                                const int2* __restrict__ gtab,
                                                float* __restrict__ out, int N) {
  __shared__ float eh[128][77];
  __shared__ int2 gs[NGRP];
  int tid = threadIdx.x;
  int n0 = blockIdx.x * 128;
  for (int idx = tid; idx < 128 * 16; idx += 256) {
    int n = idx >> 4, f4 = (idx & 15) << 2;
    int gn = n0 + n;
    float v0 = 0.f, v1 = 0.f, v2 = 0.f, v3 = 0.f;
    if (gn < N) {
      ushort4 u = *(const ushort4*)&hbf[(size_t)gn * HD + f4];
      v0 = bf2f(u.x); v1 = bf2f(u.y); v2 = bf2f(u.z); v3 = bf2f(u.w);
    }
    eh[n][f4] = v0; eh[n][f4 + 1] = v1; eh[n][f4 + 2] = v2; eh[n][f4 + 3] = v3;
  }
  for (int idx = tid; idx < 128 * 13; idx += 256) {
    int n = idx / 13, j = idx - n * 13;
    eh[n][64 + j] = (j == 0) ? 1.f : 0.f;
  }
  for (int idx = tid; idx < NGRP; idx += 256) gs[idx] = gtab[idx];
  __syncthreads();

  int w = tid >> 6, lane = tid & 63;
  int g4 = lane >> 4, c15 = lane & 15;
  float4v acc[2][3];
#pragma unroll
  for (int t = 0; t < 2; ++t)
#pragma unroll
    for (int ot = 0; ot < 3; ++ot) acc[t][ot] = (float4v){0.f, 0.f, 0.f, 0.f};
  const float* ehr0 = &eh[(w * 2 + 0) * 16 + c15][0];
  const float* ehr1 = &eh[(w * 2 + 1) * 16 + c15][0];

  for (int c = 0; c < NCHUNK; ++c) {
    const short8v b0 = *(const short8v*)&Bfrag[(((size_t)c * 3 + 0) * 64 + lane) * 8];
    const short8v b1 = *(const short8v*)&Bfrag[(((size_t)c * 3 + 1) * 64 + lane) * 8];
    const short8v b2 = *(const short8v*)&Bfrag[(((size_t)c * 3 + 2) * 64 + lane) * 8];
    int2 ml = gs[c * 4 + g4];
    int m = ml.x, l0 = ml.y;
    float hm0 = ehr0[m], hm1 = ehr1[m];
    short8v a0, a1;
#pragma unroll
    for (int e = 0; e < 8; ++e) {
      a0[e] = (short)f2bf(hm0 * ehr0[l0 + e]);
      a1[e] = (short)f2bf(hm1 * ehr1[l0 + e]);
    }
    acc[0][0] = __builtin_amdgcn_mfma_f32_16x16x32_bf16(a0, b0, acc[0][0], 0, 0, 0);
    acc[1][0] = __builtin_amdgcn_mfma_f32_16x16x32_bf16(a1, b0, acc[1][0], 0, 0, 0);
    acc[0][1] = __builtin_amdgcn_mfma_f32_16x16x32_bf16(a0, b1, acc[0][1], 0, 0, 0);
    acc[1][1] = __builtin_amdgcn_mfma_f32_16x16x32_bf16(a1, b1, acc[1][1], 0, 0, 0);
    acc[0][2] = __builtin_amdgcn_mfma_f32_16x16x32_bf16(a0, b2, acc[0][2], 0, 0, 0);
    acc[1][2] = __builtin_amdgcn_mfma_f32_16x16x32_bf16(a1, b2, acc[1][2], 0, 0, 0);
  }

  __syncthreads();  // all eh reads done; reuse as logits tile [128][41]
  float* ls = &eh[0][0];
#pragma unroll
  for (int t = 0; t < 2; ++t) {
    int rbase = (w * 2 + t) * 16 + g4 * 4;
#pragma unroll
    for (int ot = 0; ot < 3; ++ot) {
      int o = ot * 16 + c15;
      if (o < NOUT) {
#pragma unroll
        for (int r = 0; r < 4; ++r) ls[(rbase + r) * 41 + o] = acc[t][ot][r];
      }
    }
  }
  __syncthreads();
  if (tid < 128) {
    int n = n0 + tid;
    if (n < N) {
      float v[40];
      float s = 0.f;
#pragma unroll
      for (int i = 0; i < 40; ++i) { v[i] = ls[tid * 41 + i]; s = fmaf(v[i], v[i], s); }
      float un = fmaxf(sqrtf(s), 1e-15f);
      float sc = tanhf(un) / un;
      float s2 = 0.f;
#pragma unroll
      for (int i = 0; i < 40; ++i) { v[i] *= sc; s2 = fmaf(v[i], v[i], s2); }
      float ny = fmaxf(sqrtf(s2), 1e-15f);
      float maxn = 1.0f - 4e-3f;
      if (ny > maxn) {
        float f = maxn / ny;
#pragma unroll
        for (int i = 0; i < 40; ++i) v[i] *= f;
      }
      float vmax = v[0];
#pragma unroll
      for (int i = 1; i < 40; ++i) vmax = fmaxf(vmax, v[i]);
      float se = 0.f;
#pragma unroll
      for (int i = 0; i < 40; ++i) se += expf(v[i] - vmax);
      float lse = logf(se) + vmax;
      float4* q = (float4*)(out + (size_t)n * NOUT);
#pragma unroll
      for (int i = 0; i < 10; ++i) {
        float4 t;
        t.x = v[4 * i] - lse;
        t.y = v[4 * i + 1] - lse;
        t.z = v[4 * i + 2] - lse;
        t.w = v[4 * i + 3] - lse;
        q[i] = t;
      }
    }
  }
}

extern "C" void kernel_launch(void* const* d_in, const int* in_sizes, int n_in,
                              void* d_out, int out_size, void* d_ws, size_t ws_size,
                              hipStream_t stream) {
  const float* x = (const float*)d_in[0];
  const int* erow = (const int*)d_in[1];
  const int* ecol = (const int*)d_in[2];
  const float* ew = (const float*)d_in[3];
  const float* W_in = (const float*)d_in[4];
  const float* b_in = (const float*)d_in[5];
  const float* conv_W = (const float*)d_in[6];
  const float* U_W = (const float*)d_in[7];
  const float* U_b = (const float*)d_in[8];
  const float* V_W = (const float*)d_in[9];
  const float* V_b = (const float*)d_in[10];
  const float* W_out = (const float*)d_in[11];
  const float* b_out = (const float*)d_in[12];
  int N = in_sizes[0] / F_IN;
  int E = in_sizes[1];
  float* out = (float*)d_out;
  int EPAD = E + 8 * N;  // upper bound on padded edge count

  char* base = (char*)d_ws;
  size_t off = 0;
  auto alloc = [&](size_t bytes) -> void* {
    void* p = base + off;
    off += (bytes + 255) & ~(size_t)255;
    return p;
  };
  ushort* h0bf = (ushort*)alloc((size_t)N * HD * 2);
  ushort* hbfA = (ushort*)alloc((size_t)N * HD * 2);
  ushort* hbfB = (ushort*)alloc((size_t)N * HD * 2);
  ushort* xbf = (ushort*)alloc((size_t)N * 512 * 2);
  int* rowptr = (int*)alloc((size_t)(N + 1) * 4);
  int* cursor = (int*)alloc((size_t)N * 4);
  int* counts = (int*)alloc((size_t)N * 4);
  int2* colw = (int2*)alloc((size_t)EPAD * 8);
  float* Tbuf = (float*)alloc((size_t)NRANK * NOUT * 64 * 64 * 4);
  ushort* Bfrag = (ushort*)alloc((size_t)NCHUNK * 3 * 64 * 8 * 2);
  ushort* Wbf = (ushort*)alloc((size_t)64 * 512 * 2);
  ushort* Mfrag = (ushort*)alloc((size_t)NL * 512 * 8 * 2);
  float* linbuf = (float*)alloc(NOUT * 64 * 4);
  float* cbuf = (float*)alloc(NOUT * 4);
  int2* gtab = (int2*)alloc(NGRP * 8);
  int* bsum = (int*)alloc(64 * 4);
  int* boff = (int*)alloc(64 * 4);

  int G = (N + 1023) / 1024;

  k_zero<<<(EPAD + 255) / 256, 256, 0, stream>>>(counts, linbuf, cbuf, (ushort4*)Bfrag, colw, EPAD, N);
  k_count<<<(E + 255) / 256, 256, 0, stream>>>(erow, counts, E);
  k_scan1<<<G, 1024, 0, stream>>>(counts, rowptr, bsum, N);
  k_scan2<<<1, 64, 0, stream>>>(bsum, boff, G);
  k_scan3<<<G, 1024, 0, stream>>>(rowptr, cursor, boff, counts, N);
  k_fill<<<(E + 255) / 256, 256, 0, stream>>>(erow, ecol, ew, cursor, colw, E);
  k_wcvt<<<128, 256, 0, stream>>>(W_in, Wbf);
  k_xcvt<<<(N * 64 + 255) / 256, 256, 0, stream>>>(x, xbf, N);
  k_gemm_bf<<<(N + 15) / 16, 64, 0, stream>>>(xbf, Wbf, b_in, h0bf, N);
  k_mpack<<<NL, 256, 0, stream>>>(conv_W, Mfrag);
  k_gtab<<<1, 512, 0, stream>>>(gtab);
  k_T<<<NRANK * NOUT, 256, 0, stream>>>(W_out, V_W, V_b, U_W, U_b, Tbuf, linbuf, cbuf);
  k_Q<<<NOUT, 256, 0, stream>>>(U_W, Tbuf, linbuf, cbuf, b_out, gtab, Bfrag);

  const ushort* hin = h0bf;
  ushort* hout = hbfA;
  for (int l = 0; l < NL; ++l) {
    k_layer<<<(N + 31) / 32, 256, 0, stream>>>(hin, h0bf, rowptr, colw,
                                               Mfrag + (size_t)l * 512 * 8,
                                               hout, N);
    hin = hout;
    hout = (hout == hbfA) ? hbfB : hbfA;
  }
  k_logits<<<(N + 127) / 128, 256, 0, stream>>>(hin, Bfrag, gtab, out, N);
}

// Round 13
// 386.577 us; speedup vs baseline: 1.2367x; 1.0115x over previous
//
#include <hip/hip_runtime.h>
#include <cmath>

#define F_IN 500
#define HD 64
#define NL 8
#define NRANK 3
#define NOUT 40
#define NGRP 300   // 297 real (m,l0) groups of 8 + 3 zero pads -> K = 2400
#define NCHUNK 75  // 2400 / 32

typedef __attribute__((ext_vector_type(8))) short short8v;
typedef __attribute__((ext_vector_type(4))) float float4v;

__device__ __forceinline__ float bf2f(ushort u) {
  union { unsigned int i; float f; } v;
  v.i = ((unsigned int)u) << 16;
  return v.f;
}
__device__ __forceinline__ float bflo(unsigned int u) {
  union { unsigned int i; float f; } v;
  v.i = u << 16;
  return v.f;
}
__device__ __forceinline__ float bfhi(unsigned int u) {
  union { unsigned int i; float f; } v;
  v.i = u & 0xffff0000u;
  return v.f;
}
__device__ __forceinline__ ushort f2bf(float f) {
  union { float f; unsigned int i; } v;
  v.f = f;
  unsigned int b = v.i;
  return (ushort)((b + 0x7FFFu + ((b >> 16) & 1u)) >> 16);
}

// ---------------- zero init (counts, bias bufs, Bfrag) ----------------
__global__ __launch_bounds__(256) void k_zero(int* counts, float* linbuf, float* cbuf,
                                              ushort4* bfrag4, int N) {
  int i = blockIdx.x * 256 + threadIdx.x;
  if (i < N) counts[i] = 0;
  if (i < NOUT * HD) linbuf[i] = 0.f;
  if (i < NOUT) cbuf[i] = 0.f;
  if (i < NCHUNK * 3 * 64 * 2) bfrag4[i] = make_ushort4(0, 0, 0, 0);
}

__global__ __launch_bounds__(256) void k_count(const int* __restrict__ row, int* counts, int E) {
  int e = blockIdx.x * 256 + threadIdx.x;
  if (e < E) atomicAdd(&counts[row[e]], 1);
}

// ---------------- parallel scan over degrees PADDED to 8 (3 kernels) ----------------
__global__ __launch_bounds__(1024) void k_scan1(const int* __restrict__ counts, int* __restrict__ rowptr,
                                                int* __restrict__ bsum, int N) {
  __shared__ int sh[1024];
  int t = threadIdx.x, i = blockIdx.x * 1024 + t;
  int c = (i < N) ? ((counts[i] + 7) & ~7) : 0;
  sh[t] = c;
  __syncthreads();
  for (int d = 1; d < 1024; d <<= 1) {
    int v = (t >= d) ? sh[t - d] : 0;
    __syncthreads();
    sh[t] += v;
    __syncthreads();
  }
  if (i < N) rowptr[i] = sh[t] - c;  // block-local exclusive
  if (t == 1023) bsum[blockIdx.x] = sh[1023];
}

__global__ __launch_bounds__(64) void k_scan2(const int* __restrict__ bsum, int* __restrict__ boff, int G) {
  int t = threadIdx.x;
  int base = 0;
  for (int s = 0; s < G; s += 64) {
    int i = s + t;
    int v = (i < G) ? bsum[i] : 0;
    int orig = v;
    for (int d = 1; d < 64; d <<= 1) {
      int u = __shfl_up(v, d, 64);
      if (t >= d) v += u;
    }
    if (i < G) boff[i] = base + v - orig;
    base += __shfl(v, 63, 64);
  }
}

__global__ __launch_bounds__(1024) void k_scan3(int* __restrict__ rowptr, int* __restrict__ cursor,
                                                const int* __restrict__ boff,
                                                const int* __restrict__ counts, int N) {
  int i = blockIdx.x * 1024 + threadIdx.x;
  if (i < N) {
    int v = rowptr[i] + boff[blockIdx.x];
    rowptr[i] = v;
    cursor[i] = v;
    if (i == N - 1) rowptr[N] = v + ((counts[i] + 7) & ~7);
  }
}

__global__ __launch_bounds__(256) void k_fill(const int* __restrict__ row, const int* __restrict__ col,
                                              const float* __restrict__ w, int* cursor,
                                              int2* __restrict__ colw, int E) {
  int e = blockIdx.x * 256 + threadIdx.x;
  if (e < E) {
    int r = row[e];
    int p = atomicAdd(&cursor[r], 1);
    colw[p] = make_int2(col[e] * HD, __float_as_int(w[e]));  // pre-scaled element offset
  }
}

// ---------------- write zero descriptors ONLY into pad slots ----------------
__global__ __launch_bounds__(256) void k_pads(const int* __restrict__ cursor,
                                              const int* __restrict__ rowptr,
                                              int2* __restrict__ colw, int N) {
  int r = blockIdx.x * 256 + threadIdx.x;
  if (r < N) {
    int e = cursor[r], ee = rowptr[r + 1];
    for (; e < ee; ++e) colw[e] = make_int2(0, 0);
  }
}

// ---------------- W_in -> bf16 [64 cols][512 k], zero-padded ----------------
__global__ __launch_bounds__(256) void k_wcvt(const float* __restrict__ W, ushort* __restrict__ Wbf) {
  int i = blockIdx.x * 256 + threadIdx.x;
  if (i >= 64 * 512) return;
  int d = i >> 9, k = i & 511;
  Wbf[i] = (k < F_IN) ? f2bf(W[(size_t)k * HD + d]) : (ushort)0;
}

// ---------------- x fp32 -> padded bf16 [N][512], pure streaming ----------------
__global__ __launch_bounds__(256) void k_xcvt(const float* __restrict__ x, ushort* __restrict__ xbf, int N) {
  int idx = blockIdx.x * 256 + threadIdx.x;  // one 8-element group per thread
  int total = N * 64;
  if (idx >= total) return;
  int row = idx >> 6, k8 = (idx & 63) << 3;
  short8v v;
  if (k8 <= 488) {
    const float4* p = (const float4*)(x + (size_t)row * F_IN + k8);
    float4 f0 = p[0], f1 = p[1];
    v[0] = (short)f2bf(f0.x); v[1] = (short)f2bf(f0.y);
    v[2] = (short)f2bf(f0.z); v[3] = (short)f2bf(f0.w);
    v[4] = (short)f2bf(f1.x); v[5] = (short)f2bf(f1.y);
    v[6] = (short)f2bf(f1.z); v[7] = (short)f2bf(f1.w);
  } else if (k8 == 496) {
    const float4* p = (const float4*)(x + (size_t)row * F_IN + 496);
    float4 f0 = p[0];
    v[0] = (short)f2bf(f0.x); v[1] = (short)f2bf(f0.y);
    v[2] = (short)f2bf(f0.z); v[3] = (short)f2bf(f0.w);
    v[4] = 0; v[5] = 0; v[6] = 0; v[7] = 0;
  } else {
    v = (short8v){0, 0, 0, 0, 0, 0, 0, 0};
  }
  *(short8v*)&xbf[((size_t)row << 9) + k8] = v;
}

// ---------------- input GEMM via MFMA from padded bf16 x, 1 wave / 16 rows ----------------
__global__ __launch_bounds__(64) void k_gemm_bf(const ushort* __restrict__ xbf,
                                                const ushort* __restrict__ Wbf,
                                                const float* __restrict__ b,
                                                ushort* __restrict__ h0bf, int N) {
  int lane = threadIdx.x;
  int c15 = lane & 15, g4 = lane >> 4;
  int rowA = blockIdx.x * 16 + c15;
  if (rowA >= N) rowA = N - 1;  // clamp; results discarded at store
  const ushort* xr = xbf + ((size_t)rowA << 9);
  int koff = g4 * 8;
  float4v acc[4];
#pragma unroll
  for (int ct = 0; ct < 4; ++ct) acc[ct] = (float4v){0.f, 0.f, 0.f, 0.f};
#pragma unroll
  for (int kc = 0; kc < 16; ++kc) {
    int kbase = kc * 32 + koff;
    const short8v a = *(const short8v*)(xr + kbase);
#pragma unroll
    for (int ct = 0; ct < 4; ++ct) {
      const short8v bb = *(const short8v*)&Wbf[((ct * 16 + c15) << 9) + kbase];
      acc[ct] = __builtin_amdgcn_mfma_f32_16x16x32_bf16(a, bb, acc[ct], 0, 0, 0);
    }
  }
  int mbase = blockIdx.x * 16 + g4 * 4;
#pragma unroll
  for (int ct = 0; ct < 4; ++ct) {
    int d = ct * 16 + c15;
    float bias = b[d];
#pragma unroll
    for (int r = 0; r < 4; ++r) {
      int m = mbase + r;
      if (m < N) {
        float v = acc[ct][r] + bias;
        h0bf[(size_t)m * HD + d] = f2bf(fmaxf(v, 0.f));
      }
    }
  }
}

// ---------------- per-layer matvec matrix in MFMA B-frag layout (once per layer) ----------------
__global__ __launch_bounds__(256) void k_mpack(const float* __restrict__ conv_W, ushort* __restrict__ Mfrag) {
  int l = blockIdx.x;
  const float* convW = conv_W + (size_t)l * HD * HD;
  ushort* out = Mfrag + (size_t)l * 512 * 8;
  float beta = logf(0.5f / (float)(l + 1) + 1.0f);
  int tid = threadIdx.x;
  for (int f = tid; f < 512; f += 256) {
    int kc = f >> 8, ct = (f >> 6) & 3, ln = f & 63;
    int kb = kc * 32 + ((ln >> 4) << 3);
    int col = (ct << 4) + (ln & 15);
    short8v vals;
#pragma unroll
    for (int e = 0; e < 8; ++e) {
      int k = kb + e;
      float v = beta * convW[(k << 6) + col] + ((k == col) ? (1.f - beta) : 0.f);
      vals[e] = (short)f2bf(v);
    }
    *(short8v*)&out[(size_t)f * 8] = vals;
  }
}

// ---------------- GCN2 layer: one row per 8-lane group, 8 edges/iter,
// DIVERGENT loop (finished groups issue nothing), desc prefetch, MFMA matvec ----------------
__global__ __launch_bounds__(256) void k_layer(const ushort* __restrict__ hin,
                                               const ushort* __restrict__ h0bf,
                                               const int* __restrict__ rowptrP, const int2* __restrict__ colw,
                                               const ushort* __restrict__ MfragL,
                                               ushort* __restrict__ hout, int N) {
  __shared__ ushort mfrag[512][8];
  __shared__ ushort sup[32][72];
  __shared__ ushort outt[32][72];
  int tid = threadIdx.x, wv = tid >> 6, t = tid & 63;
  {  // coalesced mfrag load (8 KB)
    const short8v* src = (const short8v*)MfragL;
    short8v* dst = (short8v*)&mfrag[0][0];
    dst[tid] = src[tid];
    dst[tid + 256] = src[tid + 256];
  }
  int n0 = blockIdx.x * 32;
  int re = 0;
  if (t < 9) {
    int nn = n0 + wv * 8 + t;
    if (nn <= N) re = rowptrP[nn];
  }
  int g = t >> 3, sub = t & 7;  // lane group = row slot, octet within row
  int rw = wv * 8 + g;
  int n = n0 + rw;
  int j = __shfl(re, g, 64);
  int je = __shfl(re, g + 1, 64);
  float a0 = 0.f, a1 = 0.f, a2 = 0.f, a3 = 0.f, a4 = 0.f, a5 = 0.f, a6 = 0.f, a7 = 0.f;
  const int4* cwp = (const int4*)colw;
  const ushort* hsub = hin + sub * 8;
  bool act = j < je;
  int4 q0, q1, q2, q3;
  if (act) {
    int base = j >> 1;
    q0 = cwp[base]; q1 = cwp[base + 1]; q2 = cwp[base + 2]; q3 = cwp[base + 3];
  }
  while (act) {  // divergent: groups exit independently, no stale-gather waste
    // 8 wide gathers (16B each) issued back-to-back
    int4 g0 = *(const int4*)(hsub + (unsigned)q0.x);
    int4 g1 = *(const int4*)(hsub + (unsigned)q0.z);
    int4 g2 = *(const int4*)(hsub + (unsigned)q1.x);
    int4 g3 = *(const int4*)(hsub + (unsigned)q1.z);
    int4 g4_ = *(const int4*)(hsub + (unsigned)q2.x);
    int4 g5 = *(const int4*)(hsub + (unsigned)q2.z);
    int4 g6 = *(const int4*)(hsub + (unsigned)q3.x);
    int4 g7 = *(const int4*)(hsub + (unsigned)q3.z);
    j += 8;
    bool nact = j < je;
    int4 p0 = q0, p1 = q1, p2 = q2, p3 = q3;
    if (nact) {  // next batch's descriptors prefetched WHILE gathers are in flight
      int base = j >> 1;
      p0 = cwp[base]; p1 = cwp[base + 1]; p2 = cwp[base + 2]; p3 = cwp[base + 3];
    }
    float w0 = __int_as_float(q0.y), w1 = __int_as_float(q0.w);
    float w2 = __int_as_float(q1.y), w3 = __int_as_float(q1.w);
    float w4 = __int_as_float(q2.y), w5 = __int_as_float(q2.w);
    float w6 = __int_as_float(q3.y), w7 = __int_as_float(q3.w);
#define ACC8(gg, ww)                                        \
    a0 = fmaf(ww, bflo((unsigned)gg.x), a0);                \
    a1 = fmaf(ww, bfhi((unsigned)gg.x), a1);                \
    a2 = fmaf(ww, bflo((unsigned)gg.y), a2);                \
    a3 = fmaf(ww, bfhi((unsigned)gg.y), a3);                \
    a4 = fmaf(ww, bflo((unsigned)gg.z), a4);                \
    a5 = fmaf(ww, bfhi((unsigned)gg.z), a5);                \
    a6 = fmaf(ww, bflo((unsigned)gg.w), a6);                \
    a7 = fmaf(ww, bfhi((unsigned)gg.w), a7);
    ACC8(g0, w0) ACC8(g1, w1) ACC8(g2, w2) ACC8(g3, w3)
    ACC8(g4_, w4) ACC8(g5, w5) ACC8(g6, w6) ACC8(g7, w7)
#undef ACC8
    q0 = p0; q1 = p1; q2 = p2; q3 = p3;
    act = nact;
  }
  {
    int4 h0v = (n < N) ? *(const int4*)(h0bf + (size_t)n * HD + sub * 8)
                       : make_int4(0, 0, 0, 0);
    float s0 = 0.9f * a0 + 0.1f * bflo((unsigned)h0v.x);
    float s1 = 0.9f * a1 + 0.1f * bfhi((unsigned)h0v.x);
    float s2 = 0.9f * a2 + 0.1f * bflo((unsigned)h0v.y);
    float s3 = 0.9f * a3 + 0.1f * bfhi((unsigned)h0v.y);
    float s4 = 0.9f * a4 + 0.1f * bflo((unsigned)h0v.z);
    float s5 = 0.9f * a5 + 0.1f * bfhi((unsigned)h0v.z);
    float s6 = 0.9f * a6 + 0.1f * bflo((unsigned)h0v.w);
    float s7 = 0.9f * a7 + 0.1f * bfhi((unsigned)h0v.w);
    int4 p;
    p.x = (int)(((unsigned)f2bf(s1) << 16) | (unsigned)f2bf(s0));
    p.y = (int)(((unsigned)f2bf(s3) << 16) | (unsigned)f2bf(s2));
    p.z = (int)(((unsigned)f2bf(s5) << 16) | (unsigned)f2bf(s4));
    p.w = (int)(((unsigned)f2bf(s7) << 16) | (unsigned)f2bf(s6));
    *(int4*)&sup[rw][sub * 8] = p;
  }
  __syncthreads();
  // matvec: out = relu(sup @ M) via MFMA
  {
    int rt = wv >> 1, cp = (wv & 1) * 2;
    int c15 = t & 15, g4i = t >> 4;
    const short8v a0v = *(const short8v*)&sup[rt * 16 + c15][g4i * 8];
    const short8v a1v = *(const short8v*)&sup[rt * 16 + c15][32 + g4i * 8];
#pragma unroll
    for (int q = 0; q < 2; ++q) {
      int ct = cp + q;
      const short8v b0 = *(const short8v*)&mfrag[ct * 64 + t][0];
      const short8v b1 = *(const short8v*)&mfrag[256 + ct * 64 + t][0];
      float4v acc = (float4v){0.f, 0.f, 0.f, 0.f};
      acc = __builtin_amdgcn_mfma_f32_16x16x32_bf16(a0v, b0, acc, 0, 0, 0);
      acc = __builtin_amdgcn_mfma_f32_16x16x32_bf16(a1v, b1, acc, 0, 0, 0);
#pragma unroll
      for (int r = 0; r < 4; ++r) {
        int row = rt * 16 + g4i * 4 + r;
        outt[row][ct * 16 + c15] = f2bf(fmaxf(acc[r], 0.f));
      }
    }
  }
  __syncthreads();
  {
    int row = tid >> 3, c0 = (tid & 7) * 8;
    int nn = n0 + row;
    if (nn < N) *(short8v*)&hout[(size_t)nn * HD + c0] = *(const short8v*)&outt[row][c0];
  }
}

// ---------------- group table: g -> (m, l0) ----------------
__global__ __launch_bounds__(512) void k_gtab(int2* __restrict__ gtab) {
  int g = threadIdx.x;
  if (g >= NGRP) return;
  int m = 64, l0 = 65;
  if (g < 297) {
    int cum = 0;
    for (int mm = 0; mm < 65; ++mm) {
      int ng = (65 - mm + 7) >> 3;
      if (g < cum + ng) { m = mm; l0 = mm + (g - cum) * 8; break; }
      cum += ng;
    }
  }
  gtab[g] = make_int2(m, l0);
}

// ---------------- T[r,o] = Wo_o @ V_r^T  (+ linear/const bias terms) ----------------
__global__ __launch_bounds__(256) void k_T(const float* __restrict__ W_out, const float* __restrict__ V_W,
                                           const float* __restrict__ V_b, const float* __restrict__ U_W,
                                           const float* __restrict__ U_b,
                                           float* __restrict__ Tbuf, float* linbuf, float* cbuf) {
  int o = blockIdx.x % NOUT;
  int r = blockIdx.x / NOUT;
  __shared__ float Wo[64][65];
  __shared__ float Vs[64][65];
  __shared__ float t1[64], t2[64];
  int tid = threadIdx.x;
  int tx = tid & 15, ty = tid >> 4;
  for (int idx = tid; idx < 4096; idx += 256) {
    int m = idx >> 6, l = idx & 63;
    Wo[m][l] = W_out[(size_t)idx * NOUT + o];
    Vs[m][l] = V_W[(size_t)(r * 64 + m) * 64 + l];
  }
  __syncthreads();
  float acc[4][4] = {};
  for (int l = 0; l < 64; ++l) {
    float av[4], bv[4];
#pragma unroll
    for (int i = 0; i < 4; ++i) av[i] = Wo[ty * 4 + i][l];
#pragma unroll
    for (int j = 0; j < 4; ++j) bv[j] = Vs[tx * 4 + j][l];
#pragma unroll
    for (int i = 0; i < 4; ++i)
#pragma unroll
      for (int j = 0; j < 4; ++j) acc[i][j] = fmaf(av[i], bv[j], acc[i][j]);
  }
#pragma unroll
  for (int i = 0; i < 4; ++i)
#pragma unroll
    for (int j = 0; j < 4; ++j)
      Tbuf[(((size_t)r * NOUT + o) * 64 + ty * 4 + i) * 64 + tx * 4 + j] = acc[i][j];
  if (tid < 64) {
    float s1 = 0.f, s2 = 0.f;
    for (int l = 0; l < 64; ++l) s1 = fmaf(Wo[tid][l], V_b[r * 64 + l], s1);
    for (int m = 0; m < 64; ++m) s2 = fmaf(Wo[m][tid], U_b[r * 64 + m], s2);
    t1[tid] = s1;
    t2[tid] = s2;
  }
  __syncthreads();
  if (tid < 64) {
    float s = 0.f, s2 = 0.f;
    for (int m = 0; m < 64; ++m) s = fmaf(U_W[(size_t)(r * 64 + tid) * 64 + m], t1[m], s);
    for (int l = 0; l < 64; ++l) s2 = fmaf(Vs[tid][l], t2[l], s2);
    atomicAdd(&linbuf[o * 64 + tid], s + s2);
  }
  if (tid == 0) {
    float s = 0.f;
    for (int m = 0; m < 64; ++m) s = fmaf(U_b[r * 64 + m], t1[m], s);
    atomicAdd(&cbuf[o], s);
  }
}

// ---------------- Q_o = sum_r U_r @ T[r,o]; pack bf16 B-fragments ----------------
__global__ __launch_bounds__(256) void k_Q(const float* __restrict__ U_W, const float* __restrict__ Tbuf,
                                           const float* __restrict__ linbuf, const float* __restrict__ cbuf,
                                           const float* __restrict__ b_out,
                                           const int2* __restrict__ gtab, ushort* __restrict__ Bfrag) {
  int o = blockIdx.x;
  __shared__ float Us[64][65];
  __shared__ float Tb[64][65];
  __shared__ float Q[64][65];
  int tid = threadIdx.x, tx = tid & 15, ty = tid >> 4;
  float acc[4][4] = {};
  for (int r = 0; r < NRANK; ++r) {
    for (int idx = tid; idx < 4096; idx += 256) {
      int a = idx >> 6, mm = idx & 63;
      Us[a][mm] = U_W[(size_t)(r * 64 + a) * 64 + mm];
      Tb[a][mm] = Tbuf[(((size_t)r * NOUT + o) * 64 + a) * 64 + mm];
    }
    __syncthreads();
    for (int mm = 0; mm < 64; ++mm) {
      float av[4], bv[4];
#pragma unroll
      for (int i = 0; i < 4; ++i) av[i] = Us[ty * 4 + i][mm];
#pragma unroll
      for (int j = 0; j < 4; ++j) bv[j] = Tb[mm][tx * 4 + j];
#pragma unroll
      for (int i = 0; i < 4; ++i)
#pragma unroll
        for (int j = 0; j < 4; ++j) acc[i][j] = fmaf(av[i], bv[j], acc[i][j]);
    }
    __syncthreads();
  }
#pragma unroll
  for (int i = 0; i < 4; ++i)
#pragma unroll
    for (int j = 0; j < 4; ++j) Q[ty * 4 + i][tx * 4 + j] = acc[i][j];
  __syncthreads();
  int ot = o >> 4, o15 = o & 15;
  for (int idx = tid; idx < NGRP * 8; idx += 256) {
    int g = idx >> 3, e = idx & 7;
    int2 ml = gtab[g];
    int m = ml.x, l = ml.y + e;
    float v;
    if (l < 64) v = (m == l) ? Q[m][m] : Q[m][l] + Q[l][m];
    else if (l == 64) v = (m == 64) ? (cbuf[o] + b_out[o]) : linbuf[o * 64 + m];
    else v = 0.f;
    int c = g >> 2, g4 = g & 3;
    Bfrag[((((size_t)c * 3 + ot) * 64) + g4 * 16 + o15) * 8 + e] = f2bf(v);
  }
}

// ---------------- logits via MFMA + fused expmap0/proj/log_softmax ----------------
__global__ __launch_bounds__(256) void k_logits(const ushort* __restrict__ hbf,
                                                const ushort* __restrict__ Bfrag,
                                                const int2* __restrict__ gtab,
                                                float* __restrict__ out, int N) {
  __shared__ float eh[128][77];
  __shared__ int2 gs[NGRP];
  int tid = threadIdx.x;
  int n0 = blockIdx.x * 128;
  for (int idx = tid; idx < 128 * 16; idx += 256) {
    int n = idx >> 4, f4 = (idx & 15) << 2;
    int gn = n0 + n;
    float v0 = 0.f, v1 = 0.f, v2 = 0.f, v3 = 0.f;
    if (gn < N) {
      ushort4 u = *(const ushort4*)&hbf[(size_t)gn * HD + f4];
      v0 = bf2f(u.x); v1 = bf2f(u.y); v2 = bf2f(u.z); v3 = bf2f(u.w);
    }
    eh[n][f4] = v0; eh[n][f4 + 1] = v1; eh[n][f4 + 2] = v2; eh[n][f4 + 3] = v3;
  }
  for (int idx = tid; idx < 128 * 13; idx += 256) {
    int n = idx / 13, j = idx - n * 13;
    eh[n][64 + j] = (j == 0) ? 1.f : 0.f;
  }
  for (int idx = tid; idx < NGRP; idx += 256) gs[idx] = gtab[idx];
  __syncthreads();

  int w = tid >> 6, lane = tid & 63;
  int g4 = lane >> 4, c15 = lane & 15;
  float4v acc[2][3];
#pragma unroll
  for (int t = 0; t < 2; ++t)
#pragma unroll
    for (int ot = 0; ot < 3; ++ot) acc[t][ot] = (float4v){0.f, 0.f, 0.f, 0.f};
  const float* ehr0 = &eh[(w * 2 + 0) * 16 + c15][0];
  const float* ehr1 = &eh[(w * 2 + 1) * 16 + c15][0];

  for (int c = 0; c < NCHUNK; ++c) {
    const short8v b0 = *(const short8v*)&Bfrag[(((size_t)c * 3 + 0) * 64 + lane) * 8];
    const short8v b1 = *(const short8v*)&Bfrag[(((size_t)c * 3 + 1) * 64 + lane) * 8];
    const short8v b2 = *(const short8v*)&Bfrag[(((size_t)c * 3 + 2) * 64 + lane) * 8];
    int2 ml = gs[c * 4 + g4];
    int m = ml.x, l0 = ml.y;
    float hm0 = ehr0[m], hm1 = ehr1[m];
    short8v a0, a1;
#pragma unroll
    for (int e = 0; e < 8; ++e) {
      a0[e] = (short)f2bf(hm0 * ehr0[l0 + e]);
      a1[e] = (short)f2bf(hm1 * ehr1[l0 + e]);
    }
    acc[0][0] = __builtin_amdgcn_mfma_f32_16x16x32_bf16(a0, b0, acc[0][0], 0, 0, 0);
    acc[1][0] = __builtin_amdgcn_mfma_f32_16x16x32_bf16(a1, b0, acc[1][0], 0, 0, 0);
    acc[0][1] = __builtin_amdgcn_mfma_f32_16x16x32_bf16(a0, b1, acc[0][1], 0, 0, 0);
    acc[1][1] = __builtin_amdgcn_mfma_f32_16x16x32_bf16(a1, b1, acc[1][1], 0, 0, 0);
    acc[0][2] = __builtin_amdgcn_mfma_f32_16x16x32_bf16(a0, b2, acc[0][2], 0, 0, 0);
    acc[1][2] = __builtin_amdgcn_mfma_f32_16x16x32_bf16(a1, b2, acc[1][2], 0, 0, 0);
  }

  __syncthreads();  // all eh reads done; reuse as logits tile [128][41]
  float* ls = &eh[0][0];
#pragma unroll
  for (int t = 0; t < 2; ++t) {
    int rbase = (w * 2 + t) * 16 + g4 * 4;
#pragma unroll
    for (int ot = 0; ot < 3; ++ot) {
      int o = ot * 16 + c15;
      if (o < NOUT) {
#pragma unroll
        for (int r = 0; r < 4; ++r) ls[(rbase + r) * 41 + o] = acc[t][ot][r];
      }
    }
  }
  __syncthreads();
  if (tid < 128) {
    int n = n0 + tid;
    if (n < N) {
      float v[40];
      float s = 0.f;
#pragma unroll
      for (int i = 0; i < 40; ++i) { v[i] = ls[tid * 41 + i]; s = fmaf(v[i], v[i], s); }
      float un = fmaxf(sqrtf(s), 1e-15f);
      float sc = tanhf(un) / un;
      float s2 = 0.f;
#pragma unroll
      for (int i = 0; i < 40; ++i) { v[i] *= sc; s2 = fmaf(v[i], v[i], s2); }
      float ny = fmaxf(sqrtf(s2), 1e-15f);
      float maxn = 1.0f - 4e-3f;
      if (ny > maxn) {
        float f = maxn / ny;
#pragma unroll
        for (int i = 0; i < 40; ++i) v[i] *= f;
      }
      float vmax = v[0];
#pragma unroll
      for (int i = 1; i < 40; ++i) vmax = fmaxf(vmax, v[i]);
      float se = 0.f;
#pragma unroll
      for (int i = 0; i < 40; ++i) se += expf(v[i] - vmax);
      float lse = logf(se) + vmax;
      float4* q = (float4*)(out + (size_t)n * NOUT);
#pragma unroll
      for (int i = 0; i < 10; ++i) {
        float4 t;
        t.x = v[4 * i] - lse;
        t.y = v[4 * i + 1] - lse;
        t.z = v[4 * i + 2] - lse;
        t.w = v[4 * i + 3] - lse;
        q[i] = t;
      }
    }
  }
}

extern "C" void kernel_launch(void* const* d_in, const int* in_sizes, int n_in,
                              void* d_out, int out_size, void* d_ws, size_t ws_size,
                              hipStream_t stream) {
  const float* x = (const float*)d_in[0];
  const int* erow = (const int*)d_in[1];
  const int* ecol = (const int*)d_in[2];
  const float* ew = (const float*)d_in[3];
  const float* W_in = (const float*)d_in[4];
  const float* b_in = (const float*)d_in[5];
  const float* conv_W = (const float*)d_in[6];
  const float* U_W = (const float*)d_in[7];
  const float* U_b = (const float*)d_in[8];
  const float* V_W = (const float*)d_in[9];
  const float* V_b = (const float*)d_in[10];
  const float* W_out = (const float*)d_in[11];
  const float* b_out = (const float*)d_in[12];
  int N = in_sizes[0] / F_IN;
  int E = in_sizes[1];
  float* out = (float*)d_out;
  int EPAD = E + 8 * N;  // upper bound on padded edge count

  char* base = (char*)d_ws;
  size_t off = 0;
  auto alloc = [&](size_t bytes) -> void* {
    void* p = base + off;
    off += (bytes + 255) & ~(size_t)255;
    return p;
  };
  ushort* h0bf = (ushort*)alloc((size_t)N * HD * 2);
  ushort* hbfA = (ushort*)alloc((size_t)N * HD * 2);
  ushort* hbfB = (ushort*)alloc((size_t)N * HD * 2);
  ushort* xbf = (ushort*)alloc((size_t)N * 512 * 2);
  int* rowptr = (int*)alloc((size_t)(N + 1) * 4);
  int* cursor = (int*)alloc((size_t)N * 4);
  int* counts = (int*)alloc((size_t)N * 4);
  int2* colw = (int2*)alloc((size_t)EPAD * 8);
  float* Tbuf = (float*)alloc((size_t)NRANK * NOUT * 64 * 64 * 4);
  ushort* Bfrag = (ushort*)alloc((size_t)NCHUNK * 3 * 64 * 8 * 2);
  ushort* Wbf = (ushort*)alloc((size_t)64 * 512 * 2);
  ushort* Mfrag = (ushort*)alloc((size_t)NL * 512 * 8 * 2);
  float* linbuf = (float*)alloc(NOUT * 64 * 4);
  float* cbuf = (float*)alloc(NOUT * 4);
  int2* gtab = (int2*)alloc(NGRP * 8);
  int* bsum = (int*)alloc(64 * 4);
  int* boff = (int*)alloc(64 * 4);

  int G = (N + 1023) / 1024;

  k_zero<<<(N + 255) / 256, 256, 0, stream>>>(counts, linbuf, cbuf, (ushort4*)Bfrag, N);
  k_count<<<(E + 255) / 256, 256, 0, stream>>>(erow, counts, E);
  k_scan1<<<G, 1024, 0, stream>>>(counts, rowptr, bsum, N);
  k_scan2<<<1, 64, 0, stream>>>(bsum, boff, G);
  k_scan3<<<G, 1024, 0, stream>>>(rowptr, cursor, boff, counts, N);
  k_fill<<<(E + 255) / 256, 256, 0, stream>>>(erow, ecol, ew, cursor, colw, E);
  k_pads<<<(N + 255) / 256, 256, 0, stream>>>(cursor, rowptr, colw, N);
  k_wcvt<<<128, 256, 0, stream>>>(W_in, Wbf);
  k_xcvt<<<(N * 64 + 255) / 256, 256, 0, stream>>>(x, xbf, N);
  k_gemm_bf<<<(N + 15) / 16, 64, 0, stream>>>(xbf, Wbf, b_in, h0bf, N);
  k_mpack<<<NL, 256, 0, stream>>>(conv_W, Mfrag);
  k_gtab<<<1, 512, 0, stream>>>(gtab);
  k_T<<<NRANK * NOUT, 256, 0, stream>>>(W_out, V_W, V_b, U_W, U_b, Tbuf, linbuf, cbuf);
  k_Q<<<NOUT, 256, 0, stream>>>(U_W, Tbuf, linbuf, cbuf, b_out, gtab, Bfrag);

  const ushort* hin = h0bf;
  ushort* hout = hbfA;
  for (int l = 0; l < NL; ++l) {
    k_layer<<<(N + 31) / 32, 256, 0, stream>>>(hin, h0bf, rowptr, colw,
                                               Mfrag + (size_t)l * 512 * 8,
                                               hout, N);
    hin = hout;
    hout = (hout == hbfA) ? hbfB : hbfA;
  }
  k_logits<<<(N + 127) / 128, 256, 0, stream>>>(hin, Bfrag, gtab, out, N);
}